// Round 3
// baseline (547.535 us; speedup 1.0000x reference)
//
#include <hip/hip_runtime.h>

typedef __attribute__((ext_vector_type(8))) short bf16x8;
typedef __attribute__((ext_vector_type(4))) float f32x4;

#define DEVI static __device__ __forceinline__

constexpr float NEGV = -1e9f;

DEVI unsigned short f2b(float f) {
  union { float f; unsigned int u; } c; c.f = f;
  unsigned int lsb = (c.u >> 16) & 1u;
  return (unsigned short)((c.u + 0x7fffu + lsb) >> 16);
}
DEVI float b2f(unsigned short u) {
  union { unsigned int u; float f; } c; c.u = ((unsigned int)u) << 16;
  return c.f;
}

// ---------------- f32 -> bf16 convert, 4 elems/thread ----------------
__global__ void cvt_kernel(const float* __restrict__ x, unsigned short* __restrict__ y, int n4) {
  int i = blockIdx.x * blockDim.x + threadIdx.x;
  if (i < n4) {
    float4 v = reinterpret_cast<const float4*>(x)[i];
    ushort4 o;
    o.x = f2b(v.x); o.y = f2b(v.y); o.z = f2b(v.z); o.w = f2b(v.w);
    reinterpret_cast<ushort4*>(y)[i] = o;
  }
}

// ---------------- mask canonicalization ----------------
// The harness may pass the bool mask as packed bytes OR as int32 0/1.
// Detector: OR the first 2M words (valid under both layouts). Packed random
// 0/1 bytes -> words with bits above bit0 set; int32 0/1 -> never.
__global__ void mask_flag_zero(int* flag) { *flag = 0; }

__global__ void mask_detect(const unsigned int* __restrict__ m, int n, int* flag) {
  unsigned int v = 0;
  for (int i = blockIdx.x * blockDim.x + threadIdx.x; i < n; i += gridDim.x * blockDim.x)
    v |= m[i];
  if (v & ~1u) atomicOr(flag, 1);
}

__global__ void mask_canon_k(const void* __restrict__ mraw, unsigned char* __restrict__ mc,
                             int n4, const int* __restrict__ flag) {
  int i = blockIdx.x * blockDim.x + threadIdx.x;
  if (i >= n4) return;
  bool isbytes = (*flag != 0);
  uchar4 o;
  if (isbytes) {
    uchar4 v = reinterpret_cast<const uchar4*>(mraw)[i];
    o.x = v.x ? 1 : 0; o.y = v.y ? 1 : 0; o.z = v.z ? 1 : 0; o.w = v.w ? 1 : 0;
  } else {
    int4 v = reinterpret_cast<const int4*>(mraw)[i];
    o.x = v.x != 0; o.y = v.y != 0; o.z = v.z != 0; o.w = v.w != 0;
  }
  reinterpret_cast<uchar4*>(mc)[i] = o;
}

// ---------------- LayerNorm over D=512, one row per block, f32 out --------
__global__ __launch_bounds__(256) void ln_kernel(const float* __restrict__ q,
    const float* __restrict__ gamma, const float* __restrict__ beta,
    float* __restrict__ qn) {
  int row = blockIdx.x;
  int t = threadIdx.x;
  const float* x = q + (size_t)row * 512;
  float2 v = reinterpret_cast<const float2*>(x)[t];
  float s = v.x + v.y, s2 = v.x * v.x + v.y * v.y;
  #pragma unroll
  for (int o = 32; o; o >>= 1) { s += __shfl_xor(s, o); s2 += __shfl_xor(s2, o); }
  __shared__ float ls[4], ls2[4];
  int w = t >> 6;
  if ((t & 63) == 0) { ls[w] = s; ls2[w] = s2; }
  __syncthreads();
  float S = ls[0] + ls[1] + ls[2] + ls[3];
  float S2 = ls2[0] + ls2[1] + ls2[2] + ls2[3];
  float mu = S * (1.f / 512.f);
  float var = S2 * (1.f / 512.f) - mu * mu;
  float r = rsqrtf(var + 1e-6f);
  float g0 = gamma[t * 2], g1 = gamma[t * 2 + 1];
  float b0 = beta[t * 2], b1 = beta[t * 2 + 1];
  float2 o;
  o.x = (v.x - mu) * r * g0 + b0;
  o.y = (v.y - mu) * r * g1 + b1;
  reinterpret_cast<float2*>(qn + (size_t)row * 512)[t] = o;
}

// ---------------- split-precision GEMM: Y = X[M,512] @ W[N,512]^T ----------
__global__ __launch_bounds__(256) void gemm_split(
    const float* __restrict__ X, const float* __restrict__ W,
    unsigned short* __restrict__ Yh, unsigned short* __restrict__ Yl,
    float scale) {
  constexpr int LDT = 40;
  __shared__ __align__(16) unsigned short lXh[64 * LDT], lXl[64 * LDT];
  __shared__ __align__(16) unsigned short lWh[64 * LDT], lWl[64 * LDT];
  int t = threadIdx.x;
  int w = t >> 6, l = t & 63, lr = l & 15, lg = l >> 4;
  int mb = blockIdx.x * 64, nb = blockIdx.y * 64;
  f32x4 acc[4];
  #pragma unroll
  for (int n = 0; n < 4; n++) acc[n] = {0.f, 0.f, 0.f, 0.f};
  int sr = t >> 2, sc = (t & 3) * 8;
  for (int k0 = 0; k0 < 512; k0 += 32) {
    __syncthreads();
    #pragma unroll
    for (int half = 0; half < 2; half++) {
      const float* src = half ? &W[(size_t)(nb + sr) * 512 + k0 + sc]
                              : &X[(size_t)(mb + sr) * 512 + k0 + sc];
      unsigned short* dh = half ? lWh : lXh;
      unsigned short* dl = half ? lWl : lXl;
      float4 x0 = *reinterpret_cast<const float4*>(src);
      float4 x1 = *reinterpret_cast<const float4*>(src + 4);
      ushort4 h0, h1, l0v, l1v;
      h0.x = f2b(x0.x); l0v.x = f2b(x0.x - b2f(h0.x));
      h0.y = f2b(x0.y); l0v.y = f2b(x0.y - b2f(h0.y));
      h0.z = f2b(x0.z); l0v.z = f2b(x0.z - b2f(h0.z));
      h0.w = f2b(x0.w); l0v.w = f2b(x0.w - b2f(h0.w));
      h1.x = f2b(x1.x); l1v.x = f2b(x1.x - b2f(h1.x));
      h1.y = f2b(x1.y); l1v.y = f2b(x1.y - b2f(h1.y));
      h1.z = f2b(x1.z); l1v.z = f2b(x1.z - b2f(h1.z));
      h1.w = f2b(x1.w); l1v.w = f2b(x1.w - b2f(h1.w));
      *reinterpret_cast<ushort4*>(&dh[sr * LDT + sc]) = h0;
      *reinterpret_cast<ushort4*>(&dh[sr * LDT + sc + 4]) = h1;
      *reinterpret_cast<ushort4*>(&dl[sr * LDT + sc]) = l0v;
      *reinterpret_cast<ushort4*>(&dl[sr * LDT + sc + 4]) = l1v;
    }
    __syncthreads();
    bf16x8 ah = *reinterpret_cast<const bf16x8*>(&lXh[(w * 16 + lr) * LDT + lg * 8]);
    bf16x8 al = *reinterpret_cast<const bf16x8*>(&lXl[(w * 16 + lr) * LDT + lg * 8]);
    #pragma unroll
    for (int n = 0; n < 4; n++) {
      bf16x8 bh = *reinterpret_cast<const bf16x8*>(&lWh[(n * 16 + lr) * LDT + lg * 8]);
      bf16x8 bl = *reinterpret_cast<const bf16x8*>(&lWl[(n * 16 + lr) * LDT + lg * 8]);
      acc[n] = __builtin_amdgcn_mfma_f32_16x16x32_bf16(ah, bh, acc[n], 0, 0, 0);
      acc[n] = __builtin_amdgcn_mfma_f32_16x16x32_bf16(al, bh, acc[n], 0, 0, 0);
      acc[n] = __builtin_amdgcn_mfma_f32_16x16x32_bf16(ah, bl, acc[n], 0, 0, 0);
    }
  }
  #pragma unroll
  for (int n = 0; n < 4; n++) {
    #pragma unroll
    for (int j = 0; j < 4; j++) {
      int m = mb + w * 16 + lg * 4 + j;
      int c = nb + n * 16 + lr;
      float val = acc[n][j] * scale;
      unsigned short hi = f2b(val);
      unsigned short lo = f2b(val - b2f(hi));
      Yh[(size_t)m * 512 + c] = hi;
      Yl[(size_t)m * 512 + c] = lo;
    }
  }
}

// ---------------- GEMM (bf16 in): Y[M,N] = X @ W^T ----------
// MODE 1: bf16 out transposed to vhT [B,H,64,1024]
// MODE 2: f32 out = acc + bias[n] + resid[m,n]
template<int MODE>
__global__ __launch_bounds__(256) void gemm_bt(
    const unsigned short* __restrict__ X,
    const unsigned short* __restrict__ W,
    void* __restrict__ Yv,
    float scale,
    const float* __restrict__ bias,
    const float* __restrict__ resid) {
  constexpr int LDT = 40;
  __shared__ __align__(16) unsigned short lA[64 * LDT];
  __shared__ __align__(16) unsigned short lB[64 * LDT];
  int t = threadIdx.x;
  int w = t >> 6, l = t & 63, lr = l & 15, lg = l >> 4;
  int mb = blockIdx.x * 64, nb = blockIdx.y * 64;
  f32x4 acc[4];
  #pragma unroll
  for (int n = 0; n < 4; n++) acc[n] = {0.f, 0.f, 0.f, 0.f};
  int sr = t >> 2, sc = (t & 3) * 8;
  for (int k0 = 0; k0 < 512; k0 += 32) {
    __syncthreads();
    *reinterpret_cast<float4*>(&lA[sr * LDT + sc]) =
        *reinterpret_cast<const float4*>(&X[(size_t)(mb + sr) * 512 + k0 + sc]);
    *reinterpret_cast<float4*>(&lB[sr * LDT + sc]) =
        *reinterpret_cast<const float4*>(&W[(size_t)(nb + sr) * 512 + k0 + sc]);
    __syncthreads();
    bf16x8 a = *reinterpret_cast<const bf16x8*>(&lA[(w * 16 + lr) * LDT + lg * 8]);
    #pragma unroll
    for (int n = 0; n < 4; n++) {
      bf16x8 bb = *reinterpret_cast<const bf16x8*>(&lB[(n * 16 + lr) * LDT + lg * 8]);
      acc[n] = __builtin_amdgcn_mfma_f32_16x16x32_bf16(a, bb, acc[n], 0, 0, 0);
    }
  }
  #pragma unroll
  for (int n = 0; n < 4; n++) {
    #pragma unroll
    for (int j = 0; j < 4; j++) {
      int m = mb + w * 16 + lg * 4 + j;
      int c = nb + n * 16 + lr;
      float val = acc[n][j] * scale;
      if constexpr (MODE == 1) {
        int bb_ = m >> 10, ll = m & 1023, hh = c >> 6, dd = c & 63;
        reinterpret_cast<unsigned short*>(Yv)[((size_t)((bb_ * 8 + hh) * 64 + dd)) * 1024 + ll] = f2b(val);
      } else {
        reinterpret_cast<float*>(Yv)[(size_t)m * 512 + c] =
            val + bias[c] + resid[(size_t)m * 512 + c];
      }
    }
  }
}

// ---------------- fused attention (split-precision scores) ----------------
__global__ __launch_bounds__(256) void attn_kernel(
    const unsigned short* __restrict__ qenh, const unsigned short* __restrict__ qenl,
    const unsigned short* __restrict__ qexh, const unsigned short* __restrict__ qexl,
    const unsigned short* __restrict__ khh,  const unsigned short* __restrict__ khl,
    const unsigned short* __restrict__ vhT,  // [B,H,64,1024] bf16
    const int* __restrict__ etype,           // [B,1024]
    const unsigned char* __restrict__ mask,  // [B,1024,1024] canonical bytes
    float* __restrict__ attn_g,              // [B,H,1024,1024] f32
    unsigned short* __restrict__ pv_out) {   // [8192,512] bf16
  int qt = blockIdx.x, h = blockIdx.y, b = blockIdx.z;
  int t = threadIdx.x, w = t >> 6, l = t & 63, lr = l & 15, lg = l >> 4;
  __shared__ unsigned char evk[1024];
  __shared__ __align__(16) unsigned short pbuf[4][16][40];
  for (int i = t; i < 1024; i += 256) evk[i] = (etype[b * 1024 + i] != 0);
  __syncthreads();

  int qb = qt * 64 + w * 16;
  int qrowA = qb + lr;
  bool evA = evk[qrowA] != 0;
  const unsigned short* qh = evA ? qenh : qexh;
  const unsigned short* ql = evA ? qenl : qexl;
  size_t qoff = (size_t)(b * 1024 + qrowA) * 512 + h * 64;
  bf16x8 a0h = *reinterpret_cast<const bf16x8*>(qh + qoff + lg * 8);
  bf16x8 a1h = *reinterpret_cast<const bf16x8*>(qh + qoff + 32 + lg * 8);
  bf16x8 a0l = *reinterpret_cast<const bf16x8*>(ql + qoff + lg * 8);
  bf16x8 a1l = *reinterpret_cast<const bf16x8*>(ql + qoff + 32 + lg * 8);

  bool evq[4];
  int qrc[4];
  #pragma unroll
  for (int j = 0; j < 4; j++) { qrc[j] = qb + lg * 4 + j; evq[j] = evk[qrc[j]] != 0; }

  const size_t khbase = (size_t)b * 1024 * 512 + h * 64;
  const size_t mrow = (size_t)b * 1024 * 1024;

  // ---- pass 1: online row max + sum ----
  float mrun[4] = {-3e38f, -3e38f, -3e38f, -3e38f};
  float srun[4] = {0.f, 0.f, 0.f, 0.f};
  for (int kt = 0; kt < 64; kt++) {
    f32x4 c = {0.f, 0.f, 0.f, 0.f};
    size_t ko = khbase + (size_t)(kt * 16 + lr) * 512;
    bf16x8 b0h = *reinterpret_cast<const bf16x8*>(khh + ko + lg * 8);
    bf16x8 b1h = *reinterpret_cast<const bf16x8*>(khh + ko + 32 + lg * 8);
    bf16x8 b0l = *reinterpret_cast<const bf16x8*>(khl + ko + lg * 8);
    bf16x8 b1l = *reinterpret_cast<const bf16x8*>(khl + ko + 32 + lg * 8);
    c = __builtin_amdgcn_mfma_f32_16x16x32_bf16(a0h, b0h, c, 0, 0, 0);
    c = __builtin_amdgcn_mfma_f32_16x16x32_bf16(a1h, b1h, c, 0, 0, 0);
    c = __builtin_amdgcn_mfma_f32_16x16x32_bf16(a0l, b0h, c, 0, 0, 0);
    c = __builtin_amdgcn_mfma_f32_16x16x32_bf16(a1l, b1h, c, 0, 0, 0);
    c = __builtin_amdgcn_mfma_f32_16x16x32_bf16(a0h, b0l, c, 0, 0, 0);
    c = __builtin_amdgcn_mfma_f32_16x16x32_bf16(a1h, b1l, c, 0, 0, 0);
    int kidx = kt * 16 + lr;
    bool ek = evk[kidx] != 0;
    #pragma unroll
    for (int j = 0; j < 4; j++) {
      float s = c[j];
      float val = 0.f;
      if (ek) val = (evq[j] && mask[mrow + (size_t)qrc[j] * 1024 + kidx]) ? NEGV : s;
      float vm = val;
      vm = fmaxf(vm, __shfl_xor(vm, 1));
      vm = fmaxf(vm, __shfl_xor(vm, 2));
      vm = fmaxf(vm, __shfl_xor(vm, 4));
      vm = fmaxf(vm, __shfl_xor(vm, 8));
      float mnew = fmaxf(mrun[j], vm);
      srun[j] = srun[j] * __expf(mrun[j] - mnew) + __expf(val - mnew);
      mrun[j] = mnew;
    }
  }
  float Mr[4], rS[4];
  #pragma unroll
  for (int j = 0; j < 4; j++) {
    float s = srun[j];
    s += __shfl_xor(s, 1); s += __shfl_xor(s, 2);
    s += __shfl_xor(s, 4); s += __shfl_xor(s, 8);
    Mr[j] = mrun[j];
    rS[j] = 1.f / s;
  }

  // ---- pass 2: recompute scores, write attn, PV via LDS transpose ----
  f32x4 oacc[4];
  #pragma unroll
  for (int n = 0; n < 4; n++) oacc[n] = {0.f, 0.f, 0.f, 0.f};
  float* ag = attn_g + ((size_t)(b * 8 + h)) * 1024 * 1024;
  const unsigned short* vb_base = vhT + ((size_t)((b * 8 + h) * 64)) * 1024;
  for (int kt = 0; kt < 64; kt++) {
    f32x4 c = {0.f, 0.f, 0.f, 0.f};
    size_t ko = khbase + (size_t)(kt * 16 + lr) * 512;
    bf16x8 b0h = *reinterpret_cast<const bf16x8*>(khh + ko + lg * 8);
    bf16x8 b1h = *reinterpret_cast<const bf16x8*>(khh + ko + 32 + lg * 8);
    bf16x8 b0l = *reinterpret_cast<const bf16x8*>(khl + ko + lg * 8);
    bf16x8 b1l = *reinterpret_cast<const bf16x8*>(khl + ko + 32 + lg * 8);
    c = __builtin_amdgcn_mfma_f32_16x16x32_bf16(a0h, b0h, c, 0, 0, 0);
    c = __builtin_amdgcn_mfma_f32_16x16x32_bf16(a1h, b1h, c, 0, 0, 0);
    c = __builtin_amdgcn_mfma_f32_16x16x32_bf16(a0l, b0h, c, 0, 0, 0);
    c = __builtin_amdgcn_mfma_f32_16x16x32_bf16(a1l, b1h, c, 0, 0, 0);
    c = __builtin_amdgcn_mfma_f32_16x16x32_bf16(a0h, b0l, c, 0, 0, 0);
    c = __builtin_amdgcn_mfma_f32_16x16x32_bf16(a1h, b1l, c, 0, 0, 0);
    int kidx = kt * 16 + lr;
    bool ek = evk[kidx] != 0;
    #pragma unroll
    for (int j = 0; j < 4; j++) {
      float s = c[j];
      float val = 0.f;
      if (ek) val = (evq[j] && mask[mrow + (size_t)qrc[j] * 1024 + kidx]) ? NEGV : s;
      float p = __expf(val - Mr[j]) * rS[j];
      ag[(size_t)qrc[j] * 1024 + kidx] = p;
      pbuf[w][lg * 4 + j][(kt & 1) * 16 + lr] = f2b(p);
    }
    if (kt & 1) {
      int kc = kt >> 1;
      bf16x8 pa = *reinterpret_cast<const bf16x8*>(&pbuf[w][lr][lg * 8]);
      #pragma unroll
      for (int n = 0; n < 4; n++) {
        bf16x8 vb = *reinterpret_cast<const bf16x8*>(
            vb_base + (size_t)(n * 16 + lr) * 1024 + kc * 32 + lg * 8);
        oacc[n] = __builtin_amdgcn_mfma_f32_16x16x32_bf16(pa, vb, oacc[n], 0, 0, 0);
      }
    }
  }
  #pragma unroll
  for (int n = 0; n < 4; n++) {
    #pragma unroll
    for (int j = 0; j < 4; j++) {
      pv_out[(size_t)(b * 1024 + qrc[j]) * 512 + h * 64 + n * 16 + lr] = f2b(oacc[n][j]);
    }
  }
}

extern "C" void kernel_launch(void* const* d_in, const int* in_sizes, int n_in,
                              void* d_out, int out_size, void* d_ws, size_t ws_size,
                              hipStream_t stream) {
  (void)in_sizes; (void)n_in; (void)out_size; (void)ws_size;
  const float* q     = (const float*)d_in[0];
  const float* k     = (const float*)d_in[1];
  const float* v     = (const float*)d_in[2];
  const int* etype   = (const int*)d_in[3];
  const void* mask_raw = d_in[4];
  const float* w_qs  = (const float*)d_in[5];
  const float* w_ex  = (const float*)d_in[6];
  const float* w_ks  = (const float*)d_in[7];
  const float* w_vs  = (const float*)d_in[8];
  const float* w_fc  = (const float*)d_in[9];
  const float* b_fc  = (const float*)d_in[10];
  const float* gamma = (const float*)d_in[11];
  const float* beta  = (const float*)d_in[12];

  char* ws = (char*)d_ws;
  const size_t MB = 1024 * 1024;
  float* qn            = (float*)(ws);               // 16 MB f32 (reused for mc after gemm_split)
  unsigned char* mc    = (unsigned char*)(ws);       // 8 MB canonical mask (after qn dead)
  int* mflag           = (int*)(ws + 8 * MB);        // flag (inside old qn region)
  unsigned short* qenh = (unsigned short*)(ws + 16 * MB);
  unsigned short* qenl = (unsigned short*)(ws + 24 * MB);
  unsigned short* qexh = (unsigned short*)(ws + 32 * MB);
  unsigned short* qexl = (unsigned short*)(ws + 40 * MB);
  unsigned short* khh  = (unsigned short*)(ws + 48 * MB);
  unsigned short* khl  = (unsigned short*)(ws + 56 * MB);
  unsigned short* vbf  = (unsigned short*)(ws + 64 * MB);
  unsigned short* vhT  = (unsigned short*)(ws + 72 * MB);
  unsigned short* ao   = (unsigned short*)(ws + 80 * MB);
  unsigned short* wv   = (unsigned short*)(ws + 88 * MB);
  unsigned short* wfc  = (unsigned short*)(ws + 89 * MB);

  float* outp = (float*)d_out;
  float* attn_g = outp + (size_t)8 * 1024 * 512;

  int n4 = 8192 * 512 / 4;
  int blk = 256;
  cvt_kernel<<<dim3((n4 + blk - 1) / blk), blk, 0, stream>>>(v, vbf, n4);
  int w4 = 512 * 512 / 4;
  cvt_kernel<<<dim3((w4 + blk - 1) / blk), blk, 0, stream>>>(w_vs, wv, w4);
  cvt_kernel<<<dim3((w4 + blk - 1) / blk), blk, 0, stream>>>(w_fc, wfc, w4);
  ln_kernel<<<8192, 256, 0, stream>>>(q, gamma, beta, qn);

  dim3 gg(128, 8);
  gemm_split<<<gg, 256, 0, stream>>>(qn, w_qs, qenh, qenl, 0.125f);
  gemm_split<<<gg, 256, 0, stream>>>(qn, w_ex, qexh, qexl, 0.125f);
  gemm_split<<<gg, 256, 0, stream>>>(k, w_ks, khh, khl, 1.0f);

  // qn now dead -> canonicalize mask into its space
  const int MASK_N = 8 * 1024 * 1024;            // logical bool count
  mask_flag_zero<<<1, 1, 0, stream>>>(mflag);
  mask_detect<<<2048, 256, 0, stream>>>((const unsigned int*)mask_raw, MASK_N / 4, mflag);
  mask_canon_k<<<(MASK_N / 4 + 255) / 256, 256, 0, stream>>>(mask_raw, mc, MASK_N / 4, mflag);

  gemm_bt<1><<<gg, 256, 0, stream>>>(vbf, wv, vhT, 1.0f, nullptr, nullptr);

  attn_kernel<<<dim3(16, 8, 8), 256, 0, stream>>>(qenh, qenl, qexh, qexl, khh, khl,
                                                  vhT, etype, mc, attn_g, ao);

  gemm_bt<2><<<gg, 256, 0, stream>>>(ao, wfc, outp, 1.0f, b_fc, q);
}

// Round 4
// 471.035 us; speedup vs baseline: 1.1624x; 1.1624x over previous
//
#include <hip/hip_runtime.h>

typedef __attribute__((ext_vector_type(8))) short bf16x8;
typedef __attribute__((ext_vector_type(4))) float f32x4;

#define DEVI static __device__ __forceinline__

constexpr float NEGV = -1e9f;

DEVI unsigned short f2b(float f) {
  union { float f; unsigned int u; } c; c.f = f;
  unsigned int lsb = (c.u >> 16) & 1u;
  return (unsigned short)((c.u + 0x7fffu + lsb) >> 16);
}
DEVI float b2f(unsigned short u) {
  union { unsigned int u; float f; } c; c.u = ((unsigned int)u) << 16;
  return c.f;
}

// ---------------- f32 -> bf16 convert, 4 elems/thread ----------------
__global__ void cvt_kernel(const float* __restrict__ x, unsigned short* __restrict__ y, int n4) {
  int i = blockIdx.x * blockDim.x + threadIdx.x;
  if (i < n4) {
    float4 v = reinterpret_cast<const float4*>(x)[i];
    ushort4 o;
    o.x = f2b(v.x); o.y = f2b(v.y); o.z = f2b(v.z); o.w = f2b(v.w);
    reinterpret_cast<ushort4*>(y)[i] = o;
  }
}

// ---------------- mask canonicalization -> bit-packed [B*1024][32 u32] -----
__global__ void mask_flag_zero(int* flag) { *flag = 0; }

__global__ void mask_detect(const unsigned int* __restrict__ m, int n, int* flag) {
  unsigned int v = 0;
  for (int i = blockIdx.x * blockDim.x + threadIdx.x; i < n; i += gridDim.x * blockDim.x)
    v |= m[i];
  if (v & ~1u) atomicOr(flag, 1);
}

__global__ void mask_canon_bits(const void* __restrict__ mraw, unsigned int* __restrict__ mb,
                                int nwords, const int* __restrict__ flag) {
  int i = blockIdx.x * blockDim.x + threadIdx.x;
  if (i >= nwords) return;
  bool isbytes = (*flag != 0);
  unsigned int out = 0;
  if (isbytes) {
    const unsigned int* p = (const unsigned int*)mraw + (size_t)i * 8;
    #pragma unroll
    for (int w = 0; w < 8; w++) {
      unsigned int bw = p[w];
      out |= ((bw & 1u) << (w * 4)) | (((bw >> 8) & 1u) << (w * 4 + 1)) |
             (((bw >> 16) & 1u) << (w * 4 + 2)) | (((bw >> 24) & 1u) << (w * 4 + 3));
    }
  } else {
    const int4* p = (const int4*)mraw + (size_t)i * 8;
    #pragma unroll
    for (int w = 0; w < 8; w++) {
      int4 v = p[w];
      out |= ((v.x != 0 ? 1u : 0u) << (w * 4)) | ((v.y != 0 ? 1u : 0u) << (w * 4 + 1)) |
             ((v.z != 0 ? 1u : 0u) << (w * 4 + 2)) | ((v.w != 0 ? 1u : 0u) << (w * 4 + 3));
    }
  }
  mb[i] = out;
}

// ---------------- LayerNorm over D=512, one row per block, f32 out --------
__global__ __launch_bounds__(256) void ln_kernel(const float* __restrict__ q,
    const float* __restrict__ gamma, const float* __restrict__ beta,
    float* __restrict__ qn) {
  int row = blockIdx.x;
  int t = threadIdx.x;
  const float* x = q + (size_t)row * 512;
  float2 v = reinterpret_cast<const float2*>(x)[t];
  float s = v.x + v.y, s2 = v.x * v.x + v.y * v.y;
  #pragma unroll
  for (int o = 32; o; o >>= 1) { s += __shfl_xor(s, o); s2 += __shfl_xor(s2, o); }
  __shared__ float ls[4], ls2[4];
  int w = t >> 6;
  if ((t & 63) == 0) { ls[w] = s; ls2[w] = s2; }
  __syncthreads();
  float S = ls[0] + ls[1] + ls[2] + ls[3];
  float S2 = ls2[0] + ls2[1] + ls2[2] + ls2[3];
  float mu = S * (1.f / 512.f);
  float var = S2 * (1.f / 512.f) - mu * mu;
  float r = rsqrtf(var + 1e-6f);
  float g0 = gamma[t * 2], g1 = gamma[t * 2 + 1];
  float b0 = beta[t * 2], b1 = beta[t * 2 + 1];
  float2 o;
  o.x = (v.x - mu) * r * g0 + b0;
  o.y = (v.y - mu) * r * g1 + b1;
  reinterpret_cast<float2*>(qn + (size_t)row * 512)[t] = o;
}

// ---------------- split-precision GEMM: Y = X[M,512] @ W[N,512]^T ----------
__global__ __launch_bounds__(256) void gemm_split(
    const float* __restrict__ X, const float* __restrict__ W,
    unsigned short* __restrict__ Yh, unsigned short* __restrict__ Yl,
    float scale) {
  constexpr int LDT = 40;
  __shared__ __align__(16) unsigned short lXh[64 * LDT], lXl[64 * LDT];
  __shared__ __align__(16) unsigned short lWh[64 * LDT], lWl[64 * LDT];
  int t = threadIdx.x;
  int w = t >> 6, l = t & 63, lr = l & 15, lg = l >> 4;
  int mb = blockIdx.x * 64, nb = blockIdx.y * 64;
  f32x4 acc[4];
  #pragma unroll
  for (int n = 0; n < 4; n++) acc[n] = {0.f, 0.f, 0.f, 0.f};
  int sr = t >> 2, sc = (t & 3) * 8;
  for (int k0 = 0; k0 < 512; k0 += 32) {
    __syncthreads();
    #pragma unroll
    for (int half = 0; half < 2; half++) {
      const float* src = half ? &W[(size_t)(nb + sr) * 512 + k0 + sc]
                              : &X[(size_t)(mb + sr) * 512 + k0 + sc];
      unsigned short* dh = half ? lWh : lXh;
      unsigned short* dl = half ? lWl : lXl;
      float4 x0 = *reinterpret_cast<const float4*>(src);
      float4 x1 = *reinterpret_cast<const float4*>(src + 4);
      ushort4 h0, h1, l0v, l1v;
      h0.x = f2b(x0.x); l0v.x = f2b(x0.x - b2f(h0.x));
      h0.y = f2b(x0.y); l0v.y = f2b(x0.y - b2f(h0.y));
      h0.z = f2b(x0.z); l0v.z = f2b(x0.z - b2f(h0.z));
      h0.w = f2b(x0.w); l0v.w = f2b(x0.w - b2f(h0.w));
      h1.x = f2b(x1.x); l1v.x = f2b(x1.x - b2f(h1.x));
      h1.y = f2b(x1.y); l1v.y = f2b(x1.y - b2f(h1.y));
      h1.z = f2b(x1.z); l1v.z = f2b(x1.z - b2f(h1.z));
      h1.w = f2b(x1.w); l1v.w = f2b(x1.w - b2f(h1.w));
      *reinterpret_cast<ushort4*>(&dh[sr * LDT + sc]) = h0;
      *reinterpret_cast<ushort4*>(&dh[sr * LDT + sc + 4]) = h1;
      *reinterpret_cast<ushort4*>(&dl[sr * LDT + sc]) = l0v;
      *reinterpret_cast<ushort4*>(&dl[sr * LDT + sc + 4]) = l1v;
    }
    __syncthreads();
    bf16x8 ah = *reinterpret_cast<const bf16x8*>(&lXh[(w * 16 + lr) * LDT + lg * 8]);
    bf16x8 al = *reinterpret_cast<const bf16x8*>(&lXl[(w * 16 + lr) * LDT + lg * 8]);
    #pragma unroll
    for (int n = 0; n < 4; n++) {
      bf16x8 bh = *reinterpret_cast<const bf16x8*>(&lWh[(n * 16 + lr) * LDT + lg * 8]);
      bf16x8 bl = *reinterpret_cast<const bf16x8*>(&lWl[(n * 16 + lr) * LDT + lg * 8]);
      acc[n] = __builtin_amdgcn_mfma_f32_16x16x32_bf16(ah, bh, acc[n], 0, 0, 0);
      acc[n] = __builtin_amdgcn_mfma_f32_16x16x32_bf16(al, bh, acc[n], 0, 0, 0);
      acc[n] = __builtin_amdgcn_mfma_f32_16x16x32_bf16(ah, bl, acc[n], 0, 0, 0);
    }
  }
  #pragma unroll
  for (int n = 0; n < 4; n++) {
    #pragma unroll
    for (int j = 0; j < 4; j++) {
      int m = mb + w * 16 + lg * 4 + j;
      int c = nb + n * 16 + lr;
      float val = acc[n][j] * scale;
      unsigned short hi = f2b(val);
      unsigned short lo = f2b(val - b2f(hi));
      Yh[(size_t)m * 512 + c] = hi;
      Yl[(size_t)m * 512 + c] = lo;
    }
  }
}

// ---------------- GEMM (bf16 in): Y[M,N] = X @ W^T ----------
// MODE 1: bf16 out transposed to vhT [B,H,64,1024]
// MODE 2: f32 out = acc + bias[n] + resid[m,n]
template<int MODE>
__global__ __launch_bounds__(256) void gemm_bt(
    const unsigned short* __restrict__ X,
    const unsigned short* __restrict__ W,
    void* __restrict__ Yv,
    float scale,
    const float* __restrict__ bias,
    const float* __restrict__ resid) {
  constexpr int LDT = 40;
  __shared__ __align__(16) unsigned short lA[64 * LDT];
  __shared__ __align__(16) unsigned short lB[64 * LDT];
  int t = threadIdx.x;
  int w = t >> 6, l = t & 63, lr = l & 15, lg = l >> 4;
  int mb = blockIdx.x * 64, nb = blockIdx.y * 64;
  f32x4 acc[4];
  #pragma unroll
  for (int n = 0; n < 4; n++) acc[n] = {0.f, 0.f, 0.f, 0.f};
  int sr = t >> 2, sc = (t & 3) * 8;
  for (int k0 = 0; k0 < 512; k0 += 32) {
    __syncthreads();
    *reinterpret_cast<float4*>(&lA[sr * LDT + sc]) =
        *reinterpret_cast<const float4*>(&X[(size_t)(mb + sr) * 512 + k0 + sc]);
    *reinterpret_cast<float4*>(&lB[sr * LDT + sc]) =
        *reinterpret_cast<const float4*>(&W[(size_t)(nb + sr) * 512 + k0 + sc]);
    __syncthreads();
    bf16x8 a = *reinterpret_cast<const bf16x8*>(&lA[(w * 16 + lr) * LDT + lg * 8]);
    #pragma unroll
    for (int n = 0; n < 4; n++) {
      bf16x8 bb = *reinterpret_cast<const bf16x8*>(&lB[(n * 16 + lr) * LDT + lg * 8]);
      acc[n] = __builtin_amdgcn_mfma_f32_16x16x32_bf16(a, bb, acc[n], 0, 0, 0);
    }
  }
  #pragma unroll
  for (int n = 0; n < 4; n++) {
    #pragma unroll
    for (int j = 0; j < 4; j++) {
      int m = mb + w * 16 + lg * 4 + j;
      int c = nb + n * 16 + lr;
      float val = acc[n][j] * scale;
      if constexpr (MODE == 1) {
        int bb_ = m >> 10, ll = m & 1023, hh = c >> 6, dd = c & 63;
        reinterpret_cast<unsigned short*>(Yv)[((size_t)((bb_ * 8 + hh) * 64 + dd)) * 1024 + ll] = f2b(val);
      } else {
        reinterpret_cast<float*>(Yv)[(size_t)m * 512 + c] =
            val + bias[c] + resid[(size_t)m * 512 + c];
      }
    }
  }
}

// ---------------- fused attention (no-max softmax, LDS-bit mask) ----------
// grid (16, H=8, B=8), 256 threads = 4 waves; wave owns 16 q rows, full k range.
__global__ __launch_bounds__(256) void attn_kernel(
    const unsigned short* __restrict__ qenh, const unsigned short* __restrict__ qenl,
    const unsigned short* __restrict__ qexh, const unsigned short* __restrict__ qexl,
    const unsigned short* __restrict__ khh,  const unsigned short* __restrict__ khl,
    const unsigned short* __restrict__ vhT,  // [B,H,64,1024] bf16
    const int* __restrict__ etype,           // [B,1024]
    const unsigned int* __restrict__ mbits,  // [B*1024][32] bit-packed mask
    float* __restrict__ attn_g,              // [B,H,1024,1024] f32
    unsigned short* __restrict__ pv_out) {   // [8192,512] bf16
  int qt = blockIdx.x, h = blockIdx.y, b = blockIdx.z;
  int t = threadIdx.x, w = t >> 6, l = t & 63, lr = l & 15, lg = l >> 4;
  __shared__ unsigned char evk[1024];
  __shared__ unsigned int mlds[64 * 33];              // 64 q-rows x 32 words, +1 pad
  __shared__ __align__(16) unsigned short pbuf[4][16][40];
  for (int i = t; i < 1024; i += 256) evk[i] = (etype[b * 1024 + i] != 0);
  const unsigned int* mslice = mbits + ((size_t)(b * 1024 + qt * 64)) * 32;
  for (int i = t; i < 2048; i += 256) mlds[(i >> 5) * 33 + (i & 31)] = mslice[i];
  __syncthreads();

  int qb = qt * 64 + w * 16;
  int qrowA = qb + lr;
  bool evA = evk[qrowA] != 0;
  const unsigned short* qh = evA ? qenh : qexh;
  const unsigned short* ql = evA ? qenl : qexl;
  size_t qoff = (size_t)(b * 1024 + qrowA) * 512 + h * 64;
  bf16x8 a0h = *reinterpret_cast<const bf16x8*>(qh + qoff + lg * 8);
  bf16x8 a1h = *reinterpret_cast<const bf16x8*>(qh + qoff + 32 + lg * 8);
  bf16x8 a0l = *reinterpret_cast<const bf16x8*>(ql + qoff + lg * 8);
  bf16x8 a1l = *reinterpret_cast<const bf16x8*>(ql + qoff + 32 + lg * 8);

  bool evq[4];
  int qrc[4];   // global q row
  int qlc[4];   // block-local q row (for mlds)
  #pragma unroll
  for (int j = 0; j < 4; j++) {
    qlc[j] = w * 16 + lg * 4 + j;
    qrc[j] = qt * 64 + qlc[j];
    evq[j] = evk[qrc[j] - qt * 64 + 0] != 0;  // evk indexed by local? no: global row within batch
  }
  // evk is per-batch k/q event flags over 1024 rows; q rows use same array
  #pragma unroll
  for (int j = 0; j < 4; j++) evq[j] = evk[qrc[j]] != 0;

  const size_t khbase = (size_t)b * 1024 * 512 + h * 64;

  // ---- pass 1: denominator only (no max needed: |score| << 80) ----
  float srun[4] = {0.f, 0.f, 0.f, 0.f};
  for (int kt = 0; kt < 64; kt++) {
    f32x4 cA = {0.f, 0.f, 0.f, 0.f}, cB = {0.f, 0.f, 0.f, 0.f};
    size_t ko = khbase + (size_t)(kt * 16 + lr) * 512;
    bf16x8 b0h = *reinterpret_cast<const bf16x8*>(khh + ko + lg * 8);
    bf16x8 b1h = *reinterpret_cast<const bf16x8*>(khh + ko + 32 + lg * 8);
    bf16x8 b0l = *reinterpret_cast<const bf16x8*>(khl + ko + lg * 8);
    bf16x8 b1l = *reinterpret_cast<const bf16x8*>(khl + ko + 32 + lg * 8);
    cA = __builtin_amdgcn_mfma_f32_16x16x32_bf16(a0h, b0h, cA, 0, 0, 0);
    cB = __builtin_amdgcn_mfma_f32_16x16x32_bf16(a1h, b1h, cB, 0, 0, 0);
    cA = __builtin_amdgcn_mfma_f32_16x16x32_bf16(a0l, b0h, cA, 0, 0, 0);
    cB = __builtin_amdgcn_mfma_f32_16x16x32_bf16(a1l, b1h, cB, 0, 0, 0);
    cA = __builtin_amdgcn_mfma_f32_16x16x32_bf16(a0h, b0l, cA, 0, 0, 0);
    cB = __builtin_amdgcn_mfma_f32_16x16x32_bf16(a1h, b1l, cB, 0, 0, 0);
    int kidx = kt * 16 + lr;
    bool ek = evk[kidx] != 0;
    int wcol = kt >> 1, bitpos = ((kt & 1) << 4) + lr;
    #pragma unroll
    for (int j = 0; j < 4; j++) {
      float s = cA[j] + cB[j];
      float v0 = ek ? s : 0.f;
      bool mbit = (mlds[qlc[j] * 33 + wcol] >> bitpos) & 1;
      float val = (ek && evq[j] && mbit) ? NEGV : v0;
      srun[j] += __expf(val);
    }
  }
  float rS[4];
  #pragma unroll
  for (int j = 0; j < 4; j++) {
    float s = srun[j];
    s += __shfl_xor(s, 1); s += __shfl_xor(s, 2);
    s += __shfl_xor(s, 4); s += __shfl_xor(s, 8);
    rS[j] = 1.f / s;
  }

  // ---- pass 2: recompute scores, write attn, PV via LDS transpose ----
  f32x4 oacc[4];
  #pragma unroll
  for (int n = 0; n < 4; n++) oacc[n] = {0.f, 0.f, 0.f, 0.f};
  float* ag = attn_g + ((size_t)(b * 8 + h)) * 1024 * 1024;
  const unsigned short* vb_base = vhT + ((size_t)((b * 8 + h) * 64)) * 1024;
  for (int kt = 0; kt < 64; kt++) {
    f32x4 cA = {0.f, 0.f, 0.f, 0.f}, cB = {0.f, 0.f, 0.f, 0.f};
    size_t ko = khbase + (size_t)(kt * 16 + lr) * 512;
    bf16x8 b0h = *reinterpret_cast<const bf16x8*>(khh + ko + lg * 8);
    bf16x8 b1h = *reinterpret_cast<const bf16x8*>(khh + ko + 32 + lg * 8);
    bf16x8 b0l = *reinterpret_cast<const bf16x8*>(khl + ko + lg * 8);
    bf16x8 b1l = *reinterpret_cast<const bf16x8*>(khl + ko + 32 + lg * 8);
    cA = __builtin_amdgcn_mfma_f32_16x16x32_bf16(a0h, b0h, cA, 0, 0, 0);
    cB = __builtin_amdgcn_mfma_f32_16x16x32_bf16(a1h, b1h, cB, 0, 0, 0);
    cA = __builtin_amdgcn_mfma_f32_16x16x32_bf16(a0l, b0h, cA, 0, 0, 0);
    cB = __builtin_amdgcn_mfma_f32_16x16x32_bf16(a1l, b1h, cB, 0, 0, 0);
    cA = __builtin_amdgcn_mfma_f32_16x16x32_bf16(a0h, b0l, cA, 0, 0, 0);
    cB = __builtin_amdgcn_mfma_f32_16x16x32_bf16(a1h, b1l, cB, 0, 0, 0);
    int kidx = kt * 16 + lr;
    bool ek = evk[kidx] != 0;
    int wcol = kt >> 1, bitpos = ((kt & 1) << 4) + lr;
    #pragma unroll
    for (int j = 0; j < 4; j++) {
      float s = cA[j] + cB[j];
      float v0 = ek ? s : 0.f;
      bool mbit = (mlds[qlc[j] * 33 + wcol] >> bitpos) & 1;
      float val = (ek && evq[j] && mbit) ? NEGV : v0;
      float p = __expf(val) * rS[j];
      ag[(size_t)qrc[j] * 1024 + kidx] = p;
      pbuf[w][lg * 4 + j][(kt & 1) * 16 + lr] = f2b(p);
    }
    if (kt & 1) {
      int kc = kt >> 1;
      bf16x8 pa = *reinterpret_cast<const bf16x8*>(&pbuf[w][lr][lg * 8]);
      #pragma unroll
      for (int n = 0; n < 4; n++) {
        bf16x8 vb = *reinterpret_cast<const bf16x8*>(
            vb_base + (size_t)(n * 16 + lr) * 1024 + kc * 32 + lg * 8);
        oacc[n] = __builtin_amdgcn_mfma_f32_16x16x32_bf16(pa, vb, oacc[n], 0, 0, 0);
      }
    }
  }
  #pragma unroll
  for (int n = 0; n < 4; n++) {
    #pragma unroll
    for (int j = 0; j < 4; j++) {
      pv_out[(size_t)(b * 1024 + qrc[j]) * 512 + h * 64 + n * 16 + lr] = f2b(oacc[n][j]);
    }
  }
}

extern "C" void kernel_launch(void* const* d_in, const int* in_sizes, int n_in,
                              void* d_out, int out_size, void* d_ws, size_t ws_size,
                              hipStream_t stream) {
  (void)in_sizes; (void)n_in; (void)out_size; (void)ws_size;
  const float* q     = (const float*)d_in[0];
  const float* k     = (const float*)d_in[1];
  const float* v     = (const float*)d_in[2];
  const int* etype   = (const int*)d_in[3];
  const void* mask_raw = d_in[4];
  const float* w_qs  = (const float*)d_in[5];
  const float* w_ex  = (const float*)d_in[6];
  const float* w_ks  = (const float*)d_in[7];
  const float* w_vs  = (const float*)d_in[8];
  const float* w_fc  = (const float*)d_in[9];
  const float* b_fc  = (const float*)d_in[10];
  const float* gamma = (const float*)d_in[11];
  const float* beta  = (const float*)d_in[12];

  char* ws = (char*)d_ws;
  const size_t MB = 1024 * 1024;
  float* qn            = (float*)(ws);               // 16 MB f32 (dead after gemm_split)
  unsigned int* mbits  = (unsigned int*)(ws);        // 1 MB bit-packed mask (reuses qn space)
  int* mflag           = (int*)(ws + 8 * MB);        // flag (inside old qn region)
  unsigned short* qenh = (unsigned short*)(ws + 16 * MB);
  unsigned short* qenl = (unsigned short*)(ws + 24 * MB);
  unsigned short* qexh = (unsigned short*)(ws + 32 * MB);
  unsigned short* qexl = (unsigned short*)(ws + 40 * MB);
  unsigned short* khh  = (unsigned short*)(ws + 48 * MB);
  unsigned short* khl  = (unsigned short*)(ws + 56 * MB);
  unsigned short* vbf  = (unsigned short*)(ws + 64 * MB);
  unsigned short* vhT  = (unsigned short*)(ws + 72 * MB);
  unsigned short* ao   = (unsigned short*)(ws + 80 * MB);
  unsigned short* wv   = (unsigned short*)(ws + 88 * MB);
  unsigned short* wfc  = (unsigned short*)(ws + 89 * MB);

  float* outp = (float*)d_out;
  float* attn_g = outp + (size_t)8 * 1024 * 512;

  int n4 = 8192 * 512 / 4;
  int blk = 256;
  cvt_kernel<<<dim3((n4 + blk - 1) / blk), blk, 0, stream>>>(v, vbf, n4);
  int w4 = 512 * 512 / 4;
  cvt_kernel<<<dim3((w4 + blk - 1) / blk), blk, 0, stream>>>(w_vs, wv, w4);
  cvt_kernel<<<dim3((w4 + blk - 1) / blk), blk, 0, stream>>>(w_fc, wfc, w4);
  ln_kernel<<<8192, 256, 0, stream>>>(q, gamma, beta, qn);

  dim3 gg(128, 8);
  gemm_split<<<gg, 256, 0, stream>>>(qn, w_qs, qenh, qenl, 0.125f);
  gemm_split<<<gg, 256, 0, stream>>>(qn, w_ex, qexh, qexl, 0.125f);
  gemm_split<<<gg, 256, 0, stream>>>(k, w_ks, khh, khl, 1.0f);

  // qn now dead -> canonicalize mask (bit-packed) into its space
  const int MASK_N = 8 * 1024 * 1024;            // logical bool count
  mask_flag_zero<<<1, 1, 0, stream>>>(mflag);
  mask_detect<<<2048, 256, 0, stream>>>((const unsigned int*)mask_raw, MASK_N / 4, mflag);
  const int NWORDS = MASK_N / 32;                // 262144
  mask_canon_bits<<<(NWORDS + 255) / 256, 256, 0, stream>>>(mask_raw, mbits, NWORDS, mflag);

  gemm_bt<1><<<gg, 256, 0, stream>>>(vbf, wv, vhT, 1.0f, nullptr, nullptr);

  attn_kernel<<<dim3(16, 8, 8), 256, 0, stream>>>(qenh, qenl, qexh, qexl, khh, khl,
                                                  vhT, etype, mbits, attn_g, ao);

  gemm_bt<2><<<gg, 256, 0, stream>>>(ao, wfc, outp, 1.0f, b_fc, q);
}

// Round 5
// 309.078 us; speedup vs baseline: 1.7715x; 1.5240x over previous
//
#include <hip/hip_runtime.h>

typedef __attribute__((ext_vector_type(8))) short bf16x8;
typedef __attribute__((ext_vector_type(4))) float f32x4;

#define DEVI static __device__ __forceinline__

constexpr float NEGV = -1e9f;

DEVI unsigned short f2b(float f) {
  union { float f; unsigned int u; } c; c.f = f;
  unsigned int lsb = (c.u >> 16) & 1u;
  return (unsigned short)((c.u + 0x7fffu + lsb) >> 16);
}
DEVI float b2f(unsigned short u) {
  union { unsigned int u; float f; } c; c.u = ((unsigned int)u) << 16;
  return c.f;
}

// ---------------- f32 -> bf16 convert, 4 elems/thread ----------------
__global__ void cvt_kernel(const float* __restrict__ x, unsigned short* __restrict__ y, int n4) {
  int i = blockIdx.x * blockDim.x + threadIdx.x;
  if (i < n4) {
    float4 v = reinterpret_cast<const float4*>(x)[i];
    ushort4 o;
    o.x = f2b(v.x); o.y = f2b(v.y); o.z = f2b(v.z); o.w = f2b(v.w);
    reinterpret_cast<ushort4*>(y)[i] = o;
  }
}

// ---------------- mask canonicalization -> bit-packed [B*1024][32 u32] -----
__global__ void mask_flag_zero(int* flag) { *flag = 0; }

__global__ void mask_detect(const unsigned int* __restrict__ m, int n, int* flag) {
  unsigned int v = 0;
  for (int i = blockIdx.x * blockDim.x + threadIdx.x; i < n; i += gridDim.x * blockDim.x)
    v |= m[i];
  if (v & ~1u) atomicOr(flag, 1);
}

__global__ void mask_canon_bits(const void* __restrict__ mraw, unsigned int* __restrict__ mb,
                                int nwords, const int* __restrict__ flag) {
  int i = blockIdx.x * blockDim.x + threadIdx.x;
  if (i >= nwords) return;
  bool isbytes = (*flag != 0);
  unsigned int out = 0;
  if (isbytes) {
    const unsigned int* p = (const unsigned int*)mraw + (size_t)i * 8;
    #pragma unroll
    for (int w = 0; w < 8; w++) {
      unsigned int bw = p[w];
      out |= ((bw & 1u) << (w * 4)) | (((bw >> 8) & 1u) << (w * 4 + 1)) |
             (((bw >> 16) & 1u) << (w * 4 + 2)) | (((bw >> 24) & 1u) << (w * 4 + 3));
    }
  } else {
    const int4* p = (const int4*)mraw + (size_t)i * 8;
    #pragma unroll
    for (int w = 0; w < 8; w++) {
      int4 v = p[w];
      out |= ((v.x != 0 ? 1u : 0u) << (w * 4)) | ((v.y != 0 ? 1u : 0u) << (w * 4 + 1)) |
             ((v.z != 0 ? 1u : 0u) << (w * 4 + 2)) | ((v.w != 0 ? 1u : 0u) << (w * 4 + 3));
    }
  }
  mb[i] = out;
}

// ---------------- LayerNorm over D=512, one row per block, f32 out --------
__global__ __launch_bounds__(256) void ln_kernel(const float* __restrict__ q,
    const float* __restrict__ gamma, const float* __restrict__ beta,
    float* __restrict__ qn) {
  int row = blockIdx.x;
  int t = threadIdx.x;
  const float* x = q + (size_t)row * 512;
  float2 v = reinterpret_cast<const float2*>(x)[t];
  float s = v.x + v.y, s2 = v.x * v.x + v.y * v.y;
  #pragma unroll
  for (int o = 32; o; o >>= 1) { s += __shfl_xor(s, o); s2 += __shfl_xor(s2, o); }
  __shared__ float ls[4], ls2[4];
  int w = t >> 6;
  if ((t & 63) == 0) { ls[w] = s; ls2[w] = s2; }
  __syncthreads();
  float S = ls[0] + ls[1] + ls[2] + ls[3];
  float S2 = ls2[0] + ls2[1] + ls2[2] + ls2[3];
  float mu = S * (1.f / 512.f);
  float var = S2 * (1.f / 512.f) - mu * mu;
  float r = rsqrtf(var + 1e-6f);
  float g0 = gamma[t * 2], g1 = gamma[t * 2 + 1];
  float b0 = beta[t * 2], b1 = beta[t * 2 + 1];
  float2 o;
  o.x = (v.x - mu) * r * g0 + b0;
  o.y = (v.y - mu) * r * g1 + b1;
  reinterpret_cast<float2*>(qn + (size_t)row * 512)[t] = o;
}

// ---------------- split-precision GEMM: Y = X[M,512] @ W[N,512]^T ----------
__global__ __launch_bounds__(256) void gemm_split(
    const float* __restrict__ X, const float* __restrict__ W,
    unsigned short* __restrict__ Yh, unsigned short* __restrict__ Yl,
    float scale) {
  constexpr int LDT = 40;
  __shared__ __align__(16) unsigned short lXh[64 * LDT], lXl[64 * LDT];
  __shared__ __align__(16) unsigned short lWh[64 * LDT], lWl[64 * LDT];
  int t = threadIdx.x;
  int w = t >> 6, l = t & 63, lr = l & 15, lg = l >> 4;
  int mb = blockIdx.x * 64, nb = blockIdx.y * 64;
  f32x4 acc[4];
  #pragma unroll
  for (int n = 0; n < 4; n++) acc[n] = {0.f, 0.f, 0.f, 0.f};
  int sr = t >> 2, sc = (t & 3) * 8;
  for (int k0 = 0; k0 < 512; k0 += 32) {
    __syncthreads();
    #pragma unroll
    for (int half = 0; half < 2; half++) {
      const float* src = half ? &W[(size_t)(nb + sr) * 512 + k0 + sc]
                              : &X[(size_t)(mb + sr) * 512 + k0 + sc];
      unsigned short* dh = half ? lWh : lXh;
      unsigned short* dl = half ? lWl : lXl;
      float4 x0 = *reinterpret_cast<const float4*>(src);
      float4 x1 = *reinterpret_cast<const float4*>(src + 4);
      ushort4 h0, h1, l0v, l1v;
      h0.x = f2b(x0.x); l0v.x = f2b(x0.x - b2f(h0.x));
      h0.y = f2b(x0.y); l0v.y = f2b(x0.y - b2f(h0.y));
      h0.z = f2b(x0.z); l0v.z = f2b(x0.z - b2f(h0.z));
      h0.w = f2b(x0.w); l0v.w = f2b(x0.w - b2f(h0.w));
      h1.x = f2b(x1.x); l1v.x = f2b(x1.x - b2f(h1.x));
      h1.y = f2b(x1.y); l1v.y = f2b(x1.y - b2f(h1.y));
      h1.z = f2b(x1.z); l1v.z = f2b(x1.z - b2f(h1.z));
      h1.w = f2b(x1.w); l1v.w = f2b(x1.w - b2f(h1.w));
      *reinterpret_cast<ushort4*>(&dh[sr * LDT + sc]) = h0;
      *reinterpret_cast<ushort4*>(&dh[sr * LDT + sc + 4]) = h1;
      *reinterpret_cast<ushort4*>(&dl[sr * LDT + sc]) = l0v;
      *reinterpret_cast<ushort4*>(&dl[sr * LDT + sc + 4]) = l1v;
    }
    __syncthreads();
    bf16x8 ah = *reinterpret_cast<const bf16x8*>(&lXh[(w * 16 + lr) * LDT + lg * 8]);
    bf16x8 al = *reinterpret_cast<const bf16x8*>(&lXl[(w * 16 + lr) * LDT + lg * 8]);
    #pragma unroll
    for (int n = 0; n < 4; n++) {
      bf16x8 bh = *reinterpret_cast<const bf16x8*>(&lWh[(n * 16 + lr) * LDT + lg * 8]);
      bf16x8 bl = *reinterpret_cast<const bf16x8*>(&lWl[(n * 16 + lr) * LDT + lg * 8]);
      acc[n] = __builtin_amdgcn_mfma_f32_16x16x32_bf16(ah, bh, acc[n], 0, 0, 0);
      acc[n] = __builtin_amdgcn_mfma_f32_16x16x32_bf16(al, bh, acc[n], 0, 0, 0);
      acc[n] = __builtin_amdgcn_mfma_f32_16x16x32_bf16(ah, bl, acc[n], 0, 0, 0);
    }
  }
  #pragma unroll
  for (int n = 0; n < 4; n++) {
    #pragma unroll
    for (int j = 0; j < 4; j++) {
      int m = mb + w * 16 + lg * 4 + j;
      int c = nb + n * 16 + lr;
      float val = acc[n][j] * scale;
      unsigned short hi = f2b(val);
      unsigned short lo = f2b(val - b2f(hi));
      Yh[(size_t)m * 512 + c] = hi;
      Yl[(size_t)m * 512 + c] = lo;
    }
  }
}

// ---------------- GEMM (bf16 in): Y[M,N] = X @ W^T ----------
template<int MODE>
__global__ __launch_bounds__(256) void gemm_bt(
    const unsigned short* __restrict__ X,
    const unsigned short* __restrict__ W,
    void* __restrict__ Yv,
    float scale,
    const float* __restrict__ bias,
    const float* __restrict__ resid) {
  constexpr int LDT = 40;
  __shared__ __align__(16) unsigned short lA[64 * LDT];
  __shared__ __align__(16) unsigned short lB[64 * LDT];
  int t = threadIdx.x;
  int w = t >> 6, l = t & 63, lr = l & 15, lg = l >> 4;
  int mb = blockIdx.x * 64, nb = blockIdx.y * 64;
  f32x4 acc[4];
  #pragma unroll
  for (int n = 0; n < 4; n++) acc[n] = {0.f, 0.f, 0.f, 0.f};
  int sr = t >> 2, sc = (t & 3) * 8;
  for (int k0 = 0; k0 < 512; k0 += 32) {
    __syncthreads();
    *reinterpret_cast<float4*>(&lA[sr * LDT + sc]) =
        *reinterpret_cast<const float4*>(&X[(size_t)(mb + sr) * 512 + k0 + sc]);
    *reinterpret_cast<float4*>(&lB[sr * LDT + sc]) =
        *reinterpret_cast<const float4*>(&W[(size_t)(nb + sr) * 512 + k0 + sc]);
    __syncthreads();
    bf16x8 a = *reinterpret_cast<const bf16x8*>(&lA[(w * 16 + lr) * LDT + lg * 8]);
    #pragma unroll
    for (int n = 0; n < 4; n++) {
      bf16x8 bb = *reinterpret_cast<const bf16x8*>(&lB[(n * 16 + lr) * LDT + lg * 8]);
      acc[n] = __builtin_amdgcn_mfma_f32_16x16x32_bf16(a, bb, acc[n], 0, 0, 0);
    }
  }
  #pragma unroll
  for (int n = 0; n < 4; n++) {
    #pragma unroll
    for (int j = 0; j < 4; j++) {
      int m = mb + w * 16 + lg * 4 + j;
      int c = nb + n * 16 + lr;
      float val = acc[n][j] * scale;
      if constexpr (MODE == 1) {
        int bb_ = m >> 10, ll = m & 1023, hh = c >> 6, dd = c & 63;
        reinterpret_cast<unsigned short*>(Yv)[((size_t)((bb_ * 8 + hh) * 64 + dd)) * 1024 + ll] = f2b(val);
      } else {
        reinterpret_cast<float*>(Yv)[(size_t)m * 512 + c] =
            val + bias[c] + resid[(size_t)m * 512 + c];
      }
    }
  }
}

// ---------------- fused attention (LDS-staged K/V, dbuf, swizzled) --------
// grid (16, H=8, B=8), 256 threads = 4 waves; wave owns 16 q rows, full k.
__global__ __launch_bounds__(256) void attn_kernel(
    const unsigned short* __restrict__ qenh, const unsigned short* __restrict__ qenl,
    const unsigned short* __restrict__ qexh, const unsigned short* __restrict__ qexl,
    const unsigned short* __restrict__ khh,  const unsigned short* __restrict__ khl,
    const unsigned short* __restrict__ vhT,  // [B,H,64,1024] bf16
    const int* __restrict__ etype,           // [B,1024]
    const unsigned int* __restrict__ mbits,  // [B*1024][32] bit-packed mask
    float* __restrict__ attn_g,              // [B,H,1024,1024] f32
    unsigned short* __restrict__ pv_out) {   // [8192,512] bf16
  int qt = blockIdx.x, h = blockIdx.y, b = blockIdx.z;
  int t = threadIdx.x, w = t >> 6, l = t & 63, lr = l & 15, lg = l >> 4;
  __shared__ unsigned char evk[1024];
  __shared__ unsigned int mlds[64 * 33];
  __shared__ __align__(16) unsigned short klds[2][2][2048]; // [buf][hi/lo][32 rows x 64, swz]
  __shared__ __align__(16) unsigned short vlds[2][2048];    // [buf][64 rows x 32]
  __shared__ __align__(16) unsigned short pbuf[4][16][40];

  // q-row event flag straight from global (pre-barrier)
  int qb = qt * 64 + w * 16;
  int qrowA = qb + lr;
  bool evA = etype[b * 1024 + qrowA] != 0;
  const unsigned short* qh = evA ? qenh : qexh;
  const unsigned short* ql = evA ? qenl : qexl;
  size_t qoff = (size_t)(b * 1024 + qrowA) * 512 + h * 64;
  bf16x8 a0h = *reinterpret_cast<const bf16x8*>(qh + qoff + lg * 8);
  bf16x8 a1h = *reinterpret_cast<const bf16x8*>(qh + qoff + 32 + lg * 8);
  bf16x8 a0l = *reinterpret_cast<const bf16x8*>(ql + qoff + lg * 8);
  bf16x8 a1l = *reinterpret_cast<const bf16x8*>(ql + qoff + 32 + lg * 8);

  for (int i = t; i < 1024; i += 256) evk[i] = (etype[b * 1024 + i] != 0);
  const unsigned int* mslice = mbits + ((size_t)(b * 1024 + qt * 64)) * 32;
  for (int i = t; i < 2048; i += 256) mlds[(i >> 5) * 33 + (i & 31)] = mslice[i];

  // staging coords: 256 threads cover 32 rows x 8 (16B) blocks
  int srow = t >> 3, sb8 = t & 7;
  size_t gk0 = ((size_t)(b * 1024) + srow) * 512 + h * 64 + sb8 * 8;
  int ka = srow * 64 + ((sb8 ^ (srow & 7)) << 3);      // swizzled ushort index
  // V staging: 64 rows x 4 (16B) blocks
  int vrow = t >> 2, vb8 = t & 3;
  const unsigned short* vb_base = vhT + ((size_t)((b * 8 + h) * 64)) * 1024;
  size_t gv0 = (size_t)vrow * 1024 + vb8 * 8;
  int va = vrow * 32 + vb8 * 8;

  bool evq[4];
  int qrc[4], qlc[4];
  #pragma unroll
  for (int j = 0; j < 4; j++) {
    qlc[j] = w * 16 + lg * 4 + j;
    qrc[j] = qt * 64 + qlc[j];
  }

  const size_t khbase = 0;  // gk0 already includes b,h offsets
  (void)khbase;

  // ================= PASS 1: denominators =================
  bf16x8 prh = *reinterpret_cast<const bf16x8*>(khh + gk0);
  bf16x8 prl = *reinterpret_cast<const bf16x8*>(khl + gk0);
  __syncthreads();                       // evk/mlds visible
  #pragma unroll
  for (int j = 0; j < 4; j++) evq[j] = evk[qrc[j] - qt * 64 + qt * 64] != 0;  // = evk[qrc[j]]
  *reinterpret_cast<bf16x8*>(&klds[0][0][ka]) = prh;
  *reinterpret_cast<bf16x8*>(&klds[0][1][ka]) = prl;
  __syncthreads();

  float srun[4] = {0.f, 0.f, 0.f, 0.f};
  for (int c = 0; c < 32; c++) {
    int cur = c & 1, nxt = cur ^ 1;
    if (c < 31) {
      size_t g = gk0 + (size_t)(c + 1) * 32 * 512;
      prh = *reinterpret_cast<const bf16x8*>(khh + g);
      prl = *reinterpret_cast<const bf16x8*>(khl + g);
    }
    #pragma unroll
    for (int c2 = 0; c2 < 2; c2++) {
      int kt = c * 2 + c2;
      int row = c2 * 16 + lr;
      int r7 = row & 7;
      bf16x8 b0h = *reinterpret_cast<const bf16x8*>(&klds[cur][0][row * 64 + ((lg ^ r7) << 3)]);
      bf16x8 b1h = *reinterpret_cast<const bf16x8*>(&klds[cur][0][row * 64 + (((4 + lg) ^ r7) << 3)]);
      bf16x8 b0l = *reinterpret_cast<const bf16x8*>(&klds[cur][1][row * 64 + ((lg ^ r7) << 3)]);
      bf16x8 b1l = *reinterpret_cast<const bf16x8*>(&klds[cur][1][row * 64 + (((4 + lg) ^ r7) << 3)]);
      f32x4 cA = {0.f, 0.f, 0.f, 0.f}, cB = {0.f, 0.f, 0.f, 0.f};
      cA = __builtin_amdgcn_mfma_f32_16x16x32_bf16(a0h, b0h, cA, 0, 0, 0);
      cB = __builtin_amdgcn_mfma_f32_16x16x32_bf16(a1h, b1h, cB, 0, 0, 0);
      cA = __builtin_amdgcn_mfma_f32_16x16x32_bf16(a0l, b0h, cA, 0, 0, 0);
      cB = __builtin_amdgcn_mfma_f32_16x16x32_bf16(a1l, b1h, cB, 0, 0, 0);
      cA = __builtin_amdgcn_mfma_f32_16x16x32_bf16(a0h, b0l, cA, 0, 0, 0);
      cB = __builtin_amdgcn_mfma_f32_16x16x32_bf16(a1h, b1l, cB, 0, 0, 0);
      int kidx = kt * 16 + lr;
      bool ek = evk[kidx] != 0;
      int wcol = kt >> 1, bitpos = ((kt & 1) << 4) + lr;
      #pragma unroll
      for (int j = 0; j < 4; j++) {
        float s = cA[j] + cB[j];
        float v0 = ek ? s : 0.f;
        bool mbit = (mlds[qlc[j] * 33 + wcol] >> bitpos) & 1;
        float val = (ek && evq[j] && mbit) ? NEGV : v0;
        srun[j] += __expf(val);
      }
    }
    if (c < 31) {
      __syncthreads();
      *reinterpret_cast<bf16x8*>(&klds[nxt][0][ka]) = prh;
      *reinterpret_cast<bf16x8*>(&klds[nxt][1][ka]) = prl;
      __syncthreads();
    }
  }
  float rS[4];
  #pragma unroll
  for (int j = 0; j < 4; j++) {
    float s = srun[j];
    s += __shfl_xor(s, 1); s += __shfl_xor(s, 2);
    s += __shfl_xor(s, 4); s += __shfl_xor(s, 8);
    rS[j] = 1.f / s;
  }

  // ================= PASS 2: attn write + PV =================
  f32x4 oacc[4];
  #pragma unroll
  for (int n = 0; n < 4; n++) oacc[n] = {0.f, 0.f, 0.f, 0.f};
  float* ag = attn_g + ((size_t)(b * 8 + h)) * 1024 * 1024;

  prh = *reinterpret_cast<const bf16x8*>(khh + gk0);
  prl = *reinterpret_cast<const bf16x8*>(khl + gk0);
  bf16x8 prv = *reinterpret_cast<const bf16x8*>(vb_base + gv0);
  // klds[0] free: pass1 last read klds[1] (c=31). vlds untouched in pass1.
  *reinterpret_cast<bf16x8*>(&klds[0][0][ka]) = prh;
  *reinterpret_cast<bf16x8*>(&klds[0][1][ka]) = prl;
  *reinterpret_cast<bf16x8*>(&vlds[0][va]) = prv;
  __syncthreads();

  for (int c = 0; c < 32; c++) {
    int cur = c & 1, nxt = cur ^ 1;
    if (c < 31) {
      size_t g = gk0 + (size_t)(c + 1) * 32 * 512;
      prh = *reinterpret_cast<const bf16x8*>(khh + g);
      prl = *reinterpret_cast<const bf16x8*>(khl + g);
      prv = *reinterpret_cast<const bf16x8*>(vb_base + gv0 + (size_t)(c + 1) * 32);
    }
    #pragma unroll
    for (int c2 = 0; c2 < 2; c2++) {
      int kt = c * 2 + c2;
      int row = c2 * 16 + lr;
      int r7 = row & 7;
      bf16x8 b0h = *reinterpret_cast<const bf16x8*>(&klds[cur][0][row * 64 + ((lg ^ r7) << 3)]);
      bf16x8 b1h = *reinterpret_cast<const bf16x8*>(&klds[cur][0][row * 64 + (((4 + lg) ^ r7) << 3)]);
      bf16x8 b0l = *reinterpret_cast<const bf16x8*>(&klds[cur][1][row * 64 + ((lg ^ r7) << 3)]);
      bf16x8 b1l = *reinterpret_cast<const bf16x8*>(&klds[cur][1][row * 64 + (((4 + lg) ^ r7) << 3)]);
      f32x4 cA = {0.f, 0.f, 0.f, 0.f}, cB = {0.f, 0.f, 0.f, 0.f};
      cA = __builtin_amdgcn_mfma_f32_16x16x32_bf16(a0h, b0h, cA, 0, 0, 0);
      cB = __builtin_amdgcn_mfma_f32_16x16x32_bf16(a1h, b1h, cB, 0, 0, 0);
      cA = __builtin_amdgcn_mfma_f32_16x16x32_bf16(a0l, b0h, cA, 0, 0, 0);
      cB = __builtin_amdgcn_mfma_f32_16x16x32_bf16(a1l, b1h, cB, 0, 0, 0);
      cA = __builtin_amdgcn_mfma_f32_16x16x32_bf16(a0h, b0l, cA, 0, 0, 0);
      cB = __builtin_amdgcn_mfma_f32_16x16x32_bf16(a1h, b1l, cB, 0, 0, 0);
      int kidx = kt * 16 + lr;
      bool ek = evk[kidx] != 0;
      int wcol = kt >> 1, bitpos = ((kt & 1) << 4) + lr;
      #pragma unroll
      for (int j = 0; j < 4; j++) {
        float s = cA[j] + cB[j];
        float v0 = ek ? s : 0.f;
        bool mbit = (mlds[qlc[j] * 33 + wcol] >> bitpos) & 1;
        float val = (ek && evq[j] && mbit) ? NEGV : v0;
        float p = __expf(val) * rS[j];
        __builtin_nontemporal_store(p, &ag[(size_t)qrc[j] * 1024 + kidx]);
        pbuf[w][lg * 4 + j][(kt & 1) * 16 + lr] = f2b(p);
      }
      if (kt & 1) {
        bf16x8 pa = *reinterpret_cast<const bf16x8*>(&pbuf[w][lr][lg * 8]);
        #pragma unroll
        for (int n = 0; n < 4; n++) {
          bf16x8 vb = *reinterpret_cast<const bf16x8*>(&vlds[cur][(n * 16 + lr) * 32 + lg * 8]);
          oacc[n] = __builtin_amdgcn_mfma_f32_16x16x32_bf16(pa, vb, oacc[n], 0, 0, 0);
        }
      }
    }
    if (c < 31) {
      __syncthreads();
      *reinterpret_cast<bf16x8*>(&klds[nxt][0][ka]) = prh;
      *reinterpret_cast<bf16x8*>(&klds[nxt][1][ka]) = prl;
      *reinterpret_cast<bf16x8*>(&vlds[nxt][va]) = prv;
      __syncthreads();
    }
  }
  #pragma unroll
  for (int n = 0; n < 4; n++) {
    #pragma unroll
    for (int j = 0; j < 4; j++) {
      pv_out[(size_t)(b * 1024 + qrc[j]) * 512 + h * 64 + n * 16 + lr] = f2b(oacc[n][j]);
    }
  }
}

extern "C" void kernel_launch(void* const* d_in, const int* in_sizes, int n_in,
                              void* d_out, int out_size, void* d_ws, size_t ws_size,
                              hipStream_t stream) {
  (void)in_sizes; (void)n_in; (void)out_size; (void)ws_size;
  const float* q     = (const float*)d_in[0];
  const float* k     = (const float*)d_in[1];
  const float* v     = (const float*)d_in[2];
  const int* etype   = (const int*)d_in[3];
  const void* mask_raw = d_in[4];
  const float* w_qs  = (const float*)d_in[5];
  const float* w_ex  = (const float*)d_in[6];
  const float* w_ks  = (const float*)d_in[7];
  const float* w_vs  = (const float*)d_in[8];
  const float* w_fc  = (const float*)d_in[9];
  const float* b_fc  = (const float*)d_in[10];
  const float* gamma = (const float*)d_in[11];
  const float* beta  = (const float*)d_in[12];

  char* ws = (char*)d_ws;
  const size_t MB = 1024 * 1024;
  float* qn            = (float*)(ws);               // 16 MB f32 (dead after gemm_split)
  unsigned int* mbits  = (unsigned int*)(ws);        // 1 MB bit-packed mask (reuses qn space)
  int* mflag           = (int*)(ws + 8 * MB);        // flag (inside old qn region)
  unsigned short* qenh = (unsigned short*)(ws + 16 * MB);
  unsigned short* qenl = (unsigned short*)(ws + 24 * MB);
  unsigned short* qexh = (unsigned short*)(ws + 32 * MB);
  unsigned short* qexl = (unsigned short*)(ws + 40 * MB);
  unsigned short* khh  = (unsigned short*)(ws + 48 * MB);
  unsigned short* khl  = (unsigned short*)(ws + 56 * MB);
  unsigned short* vbf  = (unsigned short*)(ws + 64 * MB);
  unsigned short* vhT  = (unsigned short*)(ws + 72 * MB);
  unsigned short* ao   = (unsigned short*)(ws + 80 * MB);
  unsigned short* wv   = (unsigned short*)(ws + 88 * MB);
  unsigned short* wfc  = (unsigned short*)(ws + 89 * MB);

  float* outp = (float*)d_out;
  float* attn_g = outp + (size_t)8 * 1024 * 512;

  int n4 = 8192 * 512 / 4;
  int blk = 256;
  cvt_kernel<<<dim3((n4 + blk - 1) / blk), blk, 0, stream>>>(v, vbf, n4);
  int w4 = 512 * 512 / 4;
  cvt_kernel<<<dim3((w4 + blk - 1) / blk), blk, 0, stream>>>(w_vs, wv, w4);
  cvt_kernel<<<dim3((w4 + blk - 1) / blk), blk, 0, stream>>>(w_fc, wfc, w4);
  ln_kernel<<<8192, 256, 0, stream>>>(q, gamma, beta, qn);

  dim3 gg(128, 8);
  gemm_split<<<gg, 256, 0, stream>>>(qn, w_qs, qenh, qenl, 0.125f);
  gemm_split<<<gg, 256, 0, stream>>>(qn, w_ex, qexh, qexl, 0.125f);
  gemm_split<<<gg, 256, 0, stream>>>(k, w_ks, khh, khl, 1.0f);

  // qn now dead -> canonicalize mask (bit-packed) into its space
  const int MASK_N = 8 * 1024 * 1024;            // logical bool count
  mask_flag_zero<<<1, 1, 0, stream>>>(mflag);
  mask_detect<<<2048, 256, 0, stream>>>((const unsigned int*)mask_raw, MASK_N / 4, mflag);
  const int NWORDS = MASK_N / 32;                // 262144
  mask_canon_bits<<<(NWORDS + 255) / 256, 256, 0, stream>>>(mask_raw, mbits, NWORDS, mflag);

  gemm_bt<1><<<gg, 256, 0, stream>>>(vbf, wv, vhT, 1.0f, nullptr, nullptr);

  attn_kernel<<<dim3(16, 8, 8), 256, 0, stream>>>(qenh, qenl, qexh, qexl, khh, khl,
                                                  vhT, etype, mbits, attn_g, ao);

  gemm_bt<2><<<gg, 256, 0, stream>>>(ao, wfc, outp, 1.0f, b_fc, q);
}

// Round 6
// 263.822 us; speedup vs baseline: 2.0754x; 1.1715x over previous
//
#include <hip/hip_runtime.h>

typedef __attribute__((ext_vector_type(8))) short bf16x8;
typedef __attribute__((ext_vector_type(4))) float f32x4;

#define DEVI static __device__ __forceinline__

constexpr float NEGV = -1e9f;

DEVI unsigned short f2b(float f) {
  union { float f; unsigned int u; } c; c.f = f;
  unsigned int lsb = (c.u >> 16) & 1u;
  return (unsigned short)((c.u + 0x7fffu + lsb) >> 16);
}

DEVI void gload16(const unsigned short* g, unsigned short* l) {
  __builtin_amdgcn_global_load_lds(
      (const __attribute__((address_space(1))) unsigned int*)g,
      (__attribute__((address_space(3))) unsigned int*)l, 16, 0, 0);
}

// ---------------- f32 -> bf16 convert, 4 elems/thread ----------------
__global__ void cvt_kernel(const float* __restrict__ x, unsigned short* __restrict__ y, int n4) {
  int i = blockIdx.x * blockDim.x + threadIdx.x;
  if (i < n4) {
    float4 v = reinterpret_cast<const float4*>(x)[i];
    ushort4 o;
    o.x = f2b(v.x); o.y = f2b(v.y); o.z = f2b(v.z); o.w = f2b(v.w);
    reinterpret_cast<ushort4*>(y)[i] = o;
  }
}

// ---------------- mask canonicalization -> bit-packed [B*1024][32 u32] -----
__global__ void mask_flag_zero(int* flag) { *flag = 0; }

__global__ void mask_detect(const unsigned int* __restrict__ m, int n, int* flag) {
  unsigned int v = 0;
  for (int i = blockIdx.x * blockDim.x + threadIdx.x; i < n; i += gridDim.x * blockDim.x)
    v |= m[i];
  if (v & ~1u) atomicOr(flag, 1);
}

__global__ void mask_canon_bits(const void* __restrict__ mraw, unsigned int* __restrict__ mb,
                                int nwords, const int* __restrict__ flag) {
  int i = blockIdx.x * blockDim.x + threadIdx.x;
  if (i >= nwords) return;
  bool isbytes = (*flag != 0);
  unsigned int out = 0;
  if (isbytes) {
    const unsigned int* p = (const unsigned int*)mraw + (size_t)i * 8;
    #pragma unroll
    for (int w = 0; w < 8; w++) {
      unsigned int bw = p[w];
      out |= ((bw & 1u) << (w * 4)) | (((bw >> 8) & 1u) << (w * 4 + 1)) |
             (((bw >> 16) & 1u) << (w * 4 + 2)) | (((bw >> 24) & 1u) << (w * 4 + 3));
    }
  } else {
    const int4* p = (const int4*)mraw + (size_t)i * 8;
    #pragma unroll
    for (int w = 0; w < 8; w++) {
      int4 v = p[w];
      out |= ((v.x != 0 ? 1u : 0u) << (w * 4)) | ((v.y != 0 ? 1u : 0u) << (w * 4 + 1)) |
             ((v.z != 0 ? 1u : 0u) << (w * 4 + 2)) | ((v.w != 0 ? 1u : 0u) << (w * 4 + 3));
    }
  }
  mb[i] = out;
}

// ---------------- LayerNorm over D=512, one row per block, bf16 out --------
__global__ __launch_bounds__(256) void ln_kernel(const float* __restrict__ q,
    const float* __restrict__ gamma, const float* __restrict__ beta,
    unsigned short* __restrict__ qn) {
  int row = blockIdx.x;
  int t = threadIdx.x;
  const float* x = q + (size_t)row * 512;
  float2 v = reinterpret_cast<const float2*>(x)[t];
  float s = v.x + v.y, s2 = v.x * v.x + v.y * v.y;
  #pragma unroll
  for (int o = 32; o; o >>= 1) { s += __shfl_xor(s, o); s2 += __shfl_xor(s2, o); }
  __shared__ float ls[4], ls2[4];
  int w = t >> 6;
  if ((t & 63) == 0) { ls[w] = s; ls2[w] = s2; }
  __syncthreads();
  float S = ls[0] + ls[1] + ls[2] + ls[3];
  float S2 = ls2[0] + ls2[1] + ls2[2] + ls2[3];
  float mu = S * (1.f / 512.f);
  float var = S2 * (1.f / 512.f) - mu * mu;
  float r = rsqrtf(var + 1e-6f);
  float g0 = gamma[t * 2], g1 = gamma[t * 2 + 1];
  float b0 = beta[t * 2], b1 = beta[t * 2 + 1];
  ushort2 o;
  o.x = f2b((v.x - mu) * r * g0 + b0);
  o.y = f2b((v.y - mu) * r * g1 + b1);
  reinterpret_cast<ushort2*>(qn + (size_t)row * 512)[t] = o;
}

// ---------------- GEMM (bf16 in): Y[M,N] = X @ W^T ----------
// MODE 0: bf16 out [M,512], scaled
// MODE 1: bf16 out transposed to vhT [B,H,64,1024]
// MODE 2: f32 out = acc + bias[n] + resid[m,n]
template<int MODE>
__global__ __launch_bounds__(256) void gemm_bt(
    const unsigned short* __restrict__ X,
    const unsigned short* __restrict__ W,
    void* __restrict__ Yv,
    float scale,
    const float* __restrict__ bias,
    const float* __restrict__ resid) {
  constexpr int LDT = 40;
  __shared__ __align__(16) unsigned short lA[64 * LDT];
  __shared__ __align__(16) unsigned short lB[64 * LDT];
  int t = threadIdx.x;
  int w = t >> 6, l = t & 63, lr = l & 15, lg = l >> 4;
  int mb = blockIdx.x * 64, nb = blockIdx.y * 64;
  f32x4 acc[4];
  #pragma unroll
  for (int n = 0; n < 4; n++) acc[n] = {0.f, 0.f, 0.f, 0.f};
  int sr = t >> 2, sc = (t & 3) * 8;
  for (int k0 = 0; k0 < 512; k0 += 32) {
    __syncthreads();
    *reinterpret_cast<float4*>(&lA[sr * LDT + sc]) =
        *reinterpret_cast<const float4*>(&X[(size_t)(mb + sr) * 512 + k0 + sc]);
    *reinterpret_cast<float4*>(&lB[sr * LDT + sc]) =
        *reinterpret_cast<const float4*>(&W[(size_t)(nb + sr) * 512 + k0 + sc]);
    __syncthreads();
    bf16x8 a = *reinterpret_cast<const bf16x8*>(&lA[(w * 16 + lr) * LDT + lg * 8]);
    #pragma unroll
    for (int n = 0; n < 4; n++) {
      bf16x8 bb = *reinterpret_cast<const bf16x8*>(&lB[(n * 16 + lr) * LDT + lg * 8]);
      acc[n] = __builtin_amdgcn_mfma_f32_16x16x32_bf16(a, bb, acc[n], 0, 0, 0);
    }
  }
  #pragma unroll
  for (int n = 0; n < 4; n++) {
    #pragma unroll
    for (int j = 0; j < 4; j++) {
      int m = mb + w * 16 + lg * 4 + j;
      int c = nb + n * 16 + lr;
      float val = acc[n][j] * scale;
      if constexpr (MODE == 0) {
        reinterpret_cast<unsigned short*>(Yv)[(size_t)m * 512 + c] = f2b(val);
      } else if constexpr (MODE == 1) {
        int bb_ = m >> 10, ll = m & 1023, hh = c >> 6, dd = c & 63;
        reinterpret_cast<unsigned short*>(Yv)[((size_t)((bb_ * 8 + hh) * 64 + dd)) * 1024 + ll] = f2b(val);
      } else {
        reinterpret_cast<float*>(Yv)[(size_t)m * 512 + c] =
            val + bias[c] + resid[(size_t)m * 512 + c];
      }
    }
  }
}

// ---------------- fused attention (bf16, gload_lds, 1-barrier dbuf) -------
// grid (16, H=8, B=8), 256 threads = 4 waves; wave owns 16 q rows, full k.
__global__ __launch_bounds__(256) void attn_kernel(
    const unsigned short* __restrict__ qen,  // [8192,512] bf16 (pre-scaled 1/8)
    const unsigned short* __restrict__ qex,  // [8192,512] bf16 (pre-scaled 1/8)
    const unsigned short* __restrict__ kh,   // [8192,512] bf16
    const unsigned short* __restrict__ vhT,  // [B,H,64,1024] bf16
    const int* __restrict__ etype,           // [B,1024]
    const unsigned int* __restrict__ mbits,  // [B*1024][32] bit-packed mask
    float* __restrict__ attn_g,              // [B,H,1024,1024] f32
    unsigned short* __restrict__ pv_out) {   // [8192,512] bf16
  int qt = blockIdx.x, h = blockIdx.y, b = blockIdx.z;
  int t = threadIdx.x, w = t >> 6, l = t & 63, lr = l & 15, lg = l >> 4;
  __shared__ unsigned int ekbits[32];                 // event bit per k
  __shared__ unsigned int mkill[64 * 33];             // mask & evq, per q-row
  __shared__ __align__(16) unsigned short klds[2][2048]; // [buf][32 rows x 64], src-swz
  __shared__ __align__(16) unsigned short vlds[2][2048]; // [buf][64 rows x 32], src-swz
  __shared__ __align__(16) unsigned short pbuf[4][16][40];

  // Q fragments (pre-barrier, global only)
  int qb = qt * 64 + w * 16;
  int qrowA = qb + lr;
  bool evA = etype[b * 1024 + qrowA] != 0;
  const unsigned short* qp = evA ? qen : qex;
  size_t qoff = (size_t)(b * 1024 + qrowA) * 512 + h * 64;
  bf16x8 a0 = *reinterpret_cast<const bf16x8*>(qp + qoff + lg * 8);
  bf16x8 a1 = *reinterpret_cast<const bf16x8*>(qp + qoff + 32 + lg * 8);

  // event bits for k range (32 words x 32 bits)
  if (t < 32) {
    unsigned int wdd = 0;
    const int4* ep = (const int4*)(etype + b * 1024 + t * 32);
    #pragma unroll
    for (int j4 = 0; j4 < 8; j4++) {
      int4 e = ep[j4];
      wdd |= ((e.x != 0 ? 1u : 0u) << (j4 * 4)) | ((e.y != 0 ? 1u : 0u) << (j4 * 4 + 1)) |
             ((e.z != 0 ? 1u : 0u) << (j4 * 4 + 2)) | ((e.w != 0 ? 1u : 0u) << (j4 * 4 + 3));
    }
    ekbits[t] = wdd;
  }
  // kill words: mask bit AND q-row-is-en (k-event AND applied at use)
  {
    const unsigned int* mslice = mbits + ((size_t)(b * 1024 + qt * 64)) * 32;
    for (int i = t; i < 2048; i += 256) {
      int row = i >> 5, wd = i & 31;
      bool evq_row = etype[b * 1024 + qt * 64 + row] != 0;
      mkill[row * 33 + wd] = evq_row ? mslice[i] : 0u;
    }
  }

  int qrc[4], qlc[4];
  #pragma unroll
  for (int j = 0; j < 4; j++) { qlc[j] = w * 16 + lg * 4 + j; qrc[j] = qt * 64 + qlc[j]; }

  // staging coords
  int srow = t >> 3, sb8 = t & 7;
  const unsigned short* kgsrc = kh + ((size_t)(b * 1024) + srow) * 512 + h * 64
                                + ((sb8 ^ (srow & 7)) << 3);
  unsigned short* kdst0 = &klds[0][(t & 192) * 8];
  unsigned short* kdst1 = &klds[1][(t & 192) * 8];
  int vrow = t >> 2, vb4 = t & 3;
  const unsigned short* vb_base = vhT + ((size_t)((b * 8 + h) * 64)) * 1024;
  const unsigned short* vgsrc = vb_base + (size_t)vrow * 1024 + ((vb4 ^ ((vrow >> 1) & 3)) << 3);
  unsigned short* vdst0 = &vlds[0][(t & 192) * 8];
  unsigned short* vdst1 = &vlds[1][(t & 192) * 8];

  // ================= PASS 1: denominators =================
  gload16(kgsrc, kdst0);
  __syncthreads();   // stage(chunk0) done + ekbits/mkill visible

  float srun[4] = {0.f, 0.f, 0.f, 0.f};
  for (int c = 0; c < 32; c++) {
    int cur = c & 1;
    if (c < 31) gload16(kgsrc + (size_t)(c + 1) * 32 * 512, cur ? kdst0 : kdst1);
    #pragma unroll
    for (int c2 = 0; c2 < 2; c2++) {
      int kt = c * 2 + c2;
      int row = c2 * 16 + lr, r7 = row & 7;
      bf16x8 b0 = *reinterpret_cast<const bf16x8*>(&klds[cur][row * 64 + ((lg ^ r7) << 3)]);
      bf16x8 b1 = *reinterpret_cast<const bf16x8*>(&klds[cur][row * 64 + (((4 + lg) ^ r7) << 3)]);
      f32x4 cc = {0.f, 0.f, 0.f, 0.f};
      cc = __builtin_amdgcn_mfma_f32_16x16x32_bf16(a0, b0, cc, 0, 0, 0);
      cc = __builtin_amdgcn_mfma_f32_16x16x32_bf16(a1, b1, cc, 0, 0, 0);
      int wcol = kt >> 1, bitpos = ((kt & 1) << 4) + lr;
      bool ekb = (ekbits[wcol] >> bitpos) & 1;
      #pragma unroll
      for (int j = 0; j < 4; j++) {
        bool mk = (mkill[qlc[j] * 33 + wcol] >> bitpos) & 1;
        float val = ekb ? (mk ? NEGV : cc[j]) : 0.f;
        srun[j] += __expf(val);
      }
    }
    __syncthreads();
  }
  float rS[4];
  #pragma unroll
  for (int j = 0; j < 4; j++) {
    float s = srun[j];
    s += __shfl_xor(s, 1); s += __shfl_xor(s, 2);
    s += __shfl_xor(s, 4); s += __shfl_xor(s, 8);
    rS[j] = 1.f / s;
  }

  // ================= PASS 2: attn write + PV =================
  f32x4 oacc[4];
  #pragma unroll
  for (int n = 0; n < 4; n++) oacc[n] = {0.f, 0.f, 0.f, 0.f};
  float* ag = attn_g + ((size_t)(b * 8 + h)) * 1024 * 1024;

  gload16(kgsrc, kdst0);
  gload16(vgsrc, vdst0);
  __syncthreads();

  for (int c = 0; c < 32; c++) {
    int cur = c & 1;
    if (c < 31) {
      gload16(kgsrc + (size_t)(c + 1) * 32 * 512, cur ? kdst0 : kdst1);
      gload16(vgsrc + (size_t)(c + 1) * 32, cur ? vdst0 : vdst1);
    }
    #pragma unroll
    for (int c2 = 0; c2 < 2; c2++) {
      int kt = c * 2 + c2;
      int row = c2 * 16 + lr, r7 = row & 7;
      bf16x8 b0 = *reinterpret_cast<const bf16x8*>(&klds[cur][row * 64 + ((lg ^ r7) << 3)]);
      bf16x8 b1 = *reinterpret_cast<const bf16x8*>(&klds[cur][row * 64 + (((4 + lg) ^ r7) << 3)]);
      f32x4 cc = {0.f, 0.f, 0.f, 0.f};
      cc = __builtin_amdgcn_mfma_f32_16x16x32_bf16(a0, b0, cc, 0, 0, 0);
      cc = __builtin_amdgcn_mfma_f32_16x16x32_bf16(a1, b1, cc, 0, 0, 0);
      int wcol = kt >> 1, bitpos = ((kt & 1) << 4) + lr;
      bool ekb = (ekbits[wcol] >> bitpos) & 1;
      int kidx = kt * 16 + lr;
      #pragma unroll
      for (int j = 0; j < 4; j++) {
        bool mk = (mkill[qlc[j] * 33 + wcol] >> bitpos) & 1;
        float val = ekb ? (mk ? NEGV : cc[j]) : 0.f;
        float p = __expf(val) * rS[j];
        __builtin_nontemporal_store(p, &ag[(size_t)qrc[j] * 1024 + kidx]);
        pbuf[w][lg * 4 + j][(kt & 1) * 16 + lr] = f2b(p);
      }
      if (kt & 1) {
        bf16x8 pa = *reinterpret_cast<const bf16x8*>(&pbuf[w][lr][lg * 8]);
        #pragma unroll
        for (int n = 0; n < 4; n++) {
          int vr = n * 16 + lr;
          int cb = (lg ^ ((vr >> 1) & 3)) << 3;
          bf16x8 vb = *reinterpret_cast<const bf16x8*>(&vlds[cur][vr * 32 + cb]);
          oacc[n] = __builtin_amdgcn_mfma_f32_16x16x32_bf16(pa, vb, oacc[n], 0, 0, 0);
        }
      }
    }
    __syncthreads();
  }
  #pragma unroll
  for (int n = 0; n < 4; n++) {
    #pragma unroll
    for (int j = 0; j < 4; j++) {
      pv_out[(size_t)(b * 1024 + qrc[j]) * 512 + h * 64 + n * 16 + lr] = f2b(oacc[n][j]);
    }
  }
}

extern "C" void kernel_launch(void* const* d_in, const int* in_sizes, int n_in,
                              void* d_out, int out_size, void* d_ws, size_t ws_size,
                              hipStream_t stream) {
  (void)in_sizes; (void)n_in; (void)out_size; (void)ws_size;
  const float* q     = (const float*)d_in[0];
  const float* k     = (const float*)d_in[1];
  const float* v     = (const float*)d_in[2];
  const int* etype   = (const int*)d_in[3];
  const void* mask_raw = d_in[4];
  const float* w_qs  = (const float*)d_in[5];
  const float* w_ex  = (const float*)d_in[6];
  const float* w_ks  = (const float*)d_in[7];
  const float* w_vs  = (const float*)d_in[8];
  const float* w_fc  = (const float*)d_in[9];
  const float* b_fc  = (const float*)d_in[10];
  const float* gamma = (const float*)d_in[11];
  const float* beta  = (const float*)d_in[12];

  char* ws = (char*)d_ws;
  const size_t MB = 1024 * 1024;
  unsigned short* qn   = (unsigned short*)(ws);            // 8 MB bf16
  unsigned short* kbf  = (unsigned short*)(ws + 8 * MB);
  unsigned short* vbf  = (unsigned short*)(ws + 16 * MB);
  unsigned short* qen  = (unsigned short*)(ws + 24 * MB);
  unsigned short* qex  = (unsigned short*)(ws + 32 * MB);
  unsigned short* khb  = (unsigned short*)(ws + 40 * MB);
  unsigned short* vhT  = (unsigned short*)(ws + 48 * MB);
  unsigned short* ao   = (unsigned short*)(ws + 56 * MB);
  unsigned short* wq   = (unsigned short*)(ws + 64 * MB);
  unsigned short* wex  = (unsigned short*)(ws + 64 * MB + 512 * 1024);
  unsigned short* wk   = (unsigned short*)(ws + 65 * MB);
  unsigned short* wv   = (unsigned short*)(ws + 65 * MB + 512 * 1024);
  unsigned short* wfc  = (unsigned short*)(ws + 66 * MB);
  unsigned int* mbits  = (unsigned int*)(ws + 67 * MB);    // 1 MB
  int* mflag           = (int*)(ws + 68 * MB);

  float* outp = (float*)d_out;
  float* attn_g = outp + (size_t)8 * 1024 * 512;

  int n4 = 8192 * 512 / 4;
  int blk = 256;
  cvt_kernel<<<dim3((n4 + blk - 1) / blk), blk, 0, stream>>>(k, kbf, n4);
  cvt_kernel<<<dim3((n4 + blk - 1) / blk), blk, 0, stream>>>(v, vbf, n4);
  int w4 = 512 * 512 / 4;
  cvt_kernel<<<dim3((w4 + blk - 1) / blk), blk, 0, stream>>>(w_qs, wq, w4);
  cvt_kernel<<<dim3((w4 + blk - 1) / blk), blk, 0, stream>>>(w_ex, wex, w4);
  cvt_kernel<<<dim3((w4 + blk - 1) / blk), blk, 0, stream>>>(w_ks, wk, w4);
  cvt_kernel<<<dim3((w4 + blk - 1) / blk), blk, 0, stream>>>(w_vs, wv, w4);
  cvt_kernel<<<dim3((w4 + blk - 1) / blk), blk, 0, stream>>>(w_fc, wfc, w4);
  ln_kernel<<<8192, 256, 0, stream>>>(q, gamma, beta, qn);

  dim3 gg(128, 8);
  gemm_bt<0><<<gg, 256, 0, stream>>>(qn, wq, qen, 0.125f, nullptr, nullptr);
  gemm_bt<0><<<gg, 256, 0, stream>>>(qn, wex, qex, 0.125f, nullptr, nullptr);
  gemm_bt<0><<<gg, 256, 0, stream>>>(kbf, wk, khb, 1.0f, nullptr, nullptr);
  gemm_bt<1><<<gg, 256, 0, stream>>>(vbf, wv, vhT, 1.0f, nullptr, nullptr);

  const int MASK_N = 8 * 1024 * 1024;
  mask_flag_zero<<<1, 1, 0, stream>>>(mflag);
  mask_detect<<<2048, 256, 0, stream>>>((const unsigned int*)mask_raw, MASK_N / 4, mflag);
  const int NWORDS = MASK_N / 32;
  mask_canon_bits<<<(NWORDS + 255) / 256, 256, 0, stream>>>(mask_raw, mbits, NWORDS, mflag);

  attn_kernel<<<dim3(16, 8, 8), 256, 0, stream>>>(qen, qex, khb, vhT, etype, mbits,
                                                  attn_g, ao);

  gemm_bt<2><<<gg, 256, 0, stream>>>(ao, wfc, outp, 1.0f, b_fc, q);
}

// Round 7
// 261.263 us; speedup vs baseline: 2.0957x; 1.0098x over previous
//
#include <hip/hip_runtime.h>

typedef __attribute__((ext_vector_type(8))) short bf16x8;
typedef __attribute__((ext_vector_type(4))) float f32x4;

#define DEVI static __device__ __forceinline__

constexpr float NEGV = -1e9f;

DEVI unsigned short f2b(float f) {
  union { float f; unsigned int u; } c; c.f = f;
  unsigned int lsb = (c.u >> 16) & 1u;
  return (unsigned short)((c.u + 0x7fffu + lsb) >> 16);
}

DEVI void gload16(const unsigned short* g, unsigned short* l) {
  __builtin_amdgcn_global_load_lds(
      (const __attribute__((address_space(1))) unsigned int*)g,
      (__attribute__((address_space(3))) unsigned int*)l, 16, 0, 0);
}

// ---------------- mask canonicalization -> bit-packed [B*1024][32 u32] -----
__global__ void mask_detect(const unsigned int* __restrict__ m, int n, int* flag) {
  unsigned int v = 0;
  for (int i = blockIdx.x * blockDim.x + threadIdx.x; i < n; i += gridDim.x * blockDim.x)
    v |= m[i];
  if (v & ~1u) atomicOr(flag, 1);
}

__global__ void mask_canon_bits(const void* __restrict__ mraw, unsigned int* __restrict__ mb,
                                int nwords, const int* __restrict__ flag) {
  int i = blockIdx.x * blockDim.x + threadIdx.x;
  if (i >= nwords) return;
  bool isbytes = (*flag != 0);
  unsigned int out = 0;
  if (isbytes) {
    const unsigned int* p = (const unsigned int*)mraw + (size_t)i * 8;
    #pragma unroll
    for (int w = 0; w < 8; w++) {
      unsigned int bw = p[w];
      out |= ((bw & 1u) << (w * 4)) | (((bw >> 8) & 1u) << (w * 4 + 1)) |
             (((bw >> 16) & 1u) << (w * 4 + 2)) | (((bw >> 24) & 1u) << (w * 4 + 3));
    }
  } else {
    const int4* p = (const int4*)mraw + (size_t)i * 8;
    #pragma unroll
    for (int w = 0; w < 8; w++) {
      int4 v = p[w];
      out |= ((v.x != 0 ? 1u : 0u) << (w * 4)) | ((v.y != 0 ? 1u : 0u) << (w * 4 + 1)) |
             ((v.z != 0 ? 1u : 0u) << (w * 4 + 2)) | ((v.w != 0 ? 1u : 0u) << (w * 4 + 3));
    }
  }
  mb[i] = out;
}

// ---------------- LayerNorm over D=512, one row per block, bf16 out --------
__global__ __launch_bounds__(256) void ln_kernel(const float* __restrict__ q,
    const float* __restrict__ gamma, const float* __restrict__ beta,
    unsigned short* __restrict__ qn) {
  int row = blockIdx.x;
  int t = threadIdx.x;
  const float* x = q + (size_t)row * 512;
  float2 v = reinterpret_cast<const float2*>(x)[t];
  float s = v.x + v.y, s2 = v.x * v.x + v.y * v.y;
  #pragma unroll
  for (int o = 32; o; o >>= 1) { s += __shfl_xor(s, o); s2 += __shfl_xor(s2, o); }
  __shared__ float ls[4], ls2[4];
  int w = t >> 6;
  if ((t & 63) == 0) { ls[w] = s; ls2[w] = s2; }
  __syncthreads();
  float S = ls[0] + ls[1] + ls[2] + ls[3];
  float S2 = ls2[0] + ls2[1] + ls2[2] + ls2[3];
  float mu = S * (1.f / 512.f);
  float var = S2 * (1.f / 512.f) - mu * mu;
  float r = rsqrtf(var + 1e-6f);
  float g0 = gamma[t * 2], g1 = gamma[t * 2 + 1];
  float b0 = beta[t * 2], b1 = beta[t * 2 + 1];
  ushort2 o;
  o.x = f2b((v.x - mu) * r * g0 + b0);
  o.y = f2b((v.y - mu) * r * g1 + b1);
  reinterpret_cast<ushort2*>(qn + (size_t)row * 512)[t] = o;
}

// ---------------- GEMM: Y[M,N] = X[M,512] @ W[N,512]^T, fused cvt ----------
// CVX/CVW: input is f32, convert to bf16 during LDS staging.
// MODE 0: bf16 out [M,512], scaled
// MODE 1: bf16 out transposed to vhT [B,H,64,1024]
// MODE 2: f32 out = acc + bias[n] + resid[m,n]
template<int MODE, bool CVX, bool CVW>
__global__ __launch_bounds__(256) void gemm_bt(
    const void* __restrict__ Xv,
    const void* __restrict__ Wv,
    void* __restrict__ Yv,
    float scale,
    const float* __restrict__ bias,
    const float* __restrict__ resid) {
  constexpr int LDT = 40;
  __shared__ __align__(16) unsigned short lA[64 * LDT];
  __shared__ __align__(16) unsigned short lB[64 * LDT];
  int t = threadIdx.x;
  int w = t >> 6, l = t & 63, lr = l & 15, lg = l >> 4;
  int mb = blockIdx.x * 64, nb = blockIdx.y * 64;
  f32x4 acc[4];
  #pragma unroll
  for (int n = 0; n < 4; n++) acc[n] = {0.f, 0.f, 0.f, 0.f};
  int sr = t >> 2, sc = (t & 3) * 8;
  for (int k0 = 0; k0 < 512; k0 += 32) {
    __syncthreads();
    if constexpr (CVX) {
      const float* src = (const float*)Xv + (size_t)(mb + sr) * 512 + k0 + sc;
      float4 x0 = *reinterpret_cast<const float4*>(src);
      float4 x1 = *reinterpret_cast<const float4*>(src + 4);
      ushort4 h0{f2b(x0.x), f2b(x0.y), f2b(x0.z), f2b(x0.w)};
      ushort4 h1{f2b(x1.x), f2b(x1.y), f2b(x1.z), f2b(x1.w)};
      *reinterpret_cast<ushort4*>(&lA[sr * LDT + sc]) = h0;
      *reinterpret_cast<ushort4*>(&lA[sr * LDT + sc + 4]) = h1;
    } else {
      *reinterpret_cast<float4*>(&lA[sr * LDT + sc]) =
          *reinterpret_cast<const float4*>((const unsigned short*)Xv + (size_t)(mb + sr) * 512 + k0 + sc);
    }
    if constexpr (CVW) {
      const float* src = (const float*)Wv + (size_t)(nb + sr) * 512 + k0 + sc;
      float4 x0 = *reinterpret_cast<const float4*>(src);
      float4 x1 = *reinterpret_cast<const float4*>(src + 4);
      ushort4 h0{f2b(x0.x), f2b(x0.y), f2b(x0.z), f2b(x0.w)};
      ushort4 h1{f2b(x1.x), f2b(x1.y), f2b(x1.z), f2b(x1.w)};
      *reinterpret_cast<ushort4*>(&lB[sr * LDT + sc]) = h0;
      *reinterpret_cast<ushort4*>(&lB[sr * LDT + sc + 4]) = h1;
    } else {
      *reinterpret_cast<float4*>(&lB[sr * LDT + sc]) =
          *reinterpret_cast<const float4*>((const unsigned short*)Wv + (size_t)(nb + sr) * 512 + k0 + sc);
    }
    __syncthreads();
    bf16x8 a = *reinterpret_cast<const bf16x8*>(&lA[(w * 16 + lr) * LDT + lg * 8]);
    #pragma unroll
    for (int n = 0; n < 4; n++) {
      bf16x8 bb = *reinterpret_cast<const bf16x8*>(&lB[(n * 16 + lr) * LDT + lg * 8]);
      acc[n] = __builtin_amdgcn_mfma_f32_16x16x32_bf16(a, bb, acc[n], 0, 0, 0);
    }
  }
  #pragma unroll
  for (int n = 0; n < 4; n++) {
    #pragma unroll
    for (int j = 0; j < 4; j++) {
      int m = mb + w * 16 + lg * 4 + j;
      int c = nb + n * 16 + lr;
      float val = acc[n][j] * scale;
      if constexpr (MODE == 0) {
        reinterpret_cast<unsigned short*>(Yv)[(size_t)m * 512 + c] = f2b(val);
      } else if constexpr (MODE == 1) {
        int bb_ = m >> 10, ll = m & 1023, hh = c >> 6, dd = c & 63;
        reinterpret_cast<unsigned short*>(Yv)[((size_t)((bb_ * 8 + hh) * 64 + dd)) * 1024 + ll] = f2b(val);
      } else {
        reinterpret_cast<float*>(Yv)[(size_t)m * 512 + c] =
            val + bias[c] + resid[(size_t)m * 512 + c];
      }
    }
  }
}

// ---------------- fused attention (bf16, gload_lds, 1-barrier dbuf) -------
// grid (16, H=8, B=8), 256 threads = 4 waves; wave owns 16 q rows, full k.
__global__ __launch_bounds__(256) void attn_kernel(
    const unsigned short* __restrict__ qen,  // [8192,512] bf16 (pre-scaled 1/8)
    const unsigned short* __restrict__ qex,  // [8192,512] bf16 (pre-scaled 1/8)
    const unsigned short* __restrict__ kh,   // [8192,512] bf16
    const unsigned short* __restrict__ vhT,  // [B,H,64,1024] bf16
    const int* __restrict__ etype,           // [B,1024]
    const unsigned int* __restrict__ mbits,  // [B*1024][32] bit-packed mask
    float* __restrict__ attn_g,              // [B,H,1024,1024] f32
    unsigned short* __restrict__ pv_out) {   // [8192,512] bf16
  int qt = blockIdx.x, h = blockIdx.y, b = blockIdx.z;
  int t = threadIdx.x, w = t >> 6, l = t & 63, lr = l & 15, lg = l >> 4;
  __shared__ unsigned int ekbits[32];                 // event bit per k
  __shared__ unsigned int mkill[64 * 33];             // mask & evq, per q-row
  __shared__ __align__(16) unsigned short klds[2][2048]; // [buf][32 rows x 64], src-swz
  __shared__ __align__(16) unsigned short vlds[2][2048]; // [buf][64 rows x 32], src-swz
  __shared__ __align__(16) unsigned short pbuf[4][16][40];

  // Q fragments (pre-barrier, global only)
  int qb = qt * 64 + w * 16;
  int qrowA = qb + lr;
  bool evA = etype[b * 1024 + qrowA] != 0;
  const unsigned short* qp = evA ? qen : qex;
  size_t qoff = (size_t)(b * 1024 + qrowA) * 512 + h * 64;
  bf16x8 a0 = *reinterpret_cast<const bf16x8*>(qp + qoff + lg * 8);
  bf16x8 a1 = *reinterpret_cast<const bf16x8*>(qp + qoff + 32 + lg * 8);

  // event bits for k range (32 words x 32 bits)
  if (t < 32) {
    unsigned int wdd = 0;
    const int4* ep = (const int4*)(etype + b * 1024 + t * 32);
    #pragma unroll
    for (int j4 = 0; j4 < 8; j4++) {
      int4 e = ep[j4];
      wdd |= ((e.x != 0 ? 1u : 0u) << (j4 * 4)) | ((e.y != 0 ? 1u : 0u) << (j4 * 4 + 1)) |
             ((e.z != 0 ? 1u : 0u) << (j4 * 4 + 2)) | ((e.w != 0 ? 1u : 0u) << (j4 * 4 + 3));
    }
    ekbits[t] = wdd;
  }
  // kill words: mask bit AND q-row-is-en
  {
    const unsigned int* mslice = mbits + ((size_t)(b * 1024 + qt * 64)) * 32;
    for (int i = t; i < 2048; i += 256) {
      int row = i >> 5, wd = i & 31;
      bool evq_row = etype[b * 1024 + qt * 64 + row] != 0;
      mkill[row * 33 + wd] = evq_row ? mslice[i] : 0u;
    }
  }

  int qrc[4], qlc[4];
  #pragma unroll
  for (int j = 0; j < 4; j++) { qlc[j] = w * 16 + lg * 4 + j; qrc[j] = qt * 64 + qlc[j]; }

  // staging coords
  int srow = t >> 3, sb8 = t & 7;
  const unsigned short* kgsrc = kh + ((size_t)(b * 1024) + srow) * 512 + h * 64
                                + ((sb8 ^ (srow & 7)) << 3);
  unsigned short* kdst0 = &klds[0][(t & 192) * 8];
  unsigned short* kdst1 = &klds[1][(t & 192) * 8];
  int vrow = t >> 2, vb4 = t & 3;
  const unsigned short* vb_base = vhT + ((size_t)((b * 8 + h) * 64)) * 1024;
  const unsigned short* vgsrc = vb_base + (size_t)vrow * 1024 + ((vb4 ^ ((vrow >> 1) & 3)) << 3);
  unsigned short* vdst0 = &vlds[0][(t & 192) * 8];
  unsigned short* vdst1 = &vlds[1][(t & 192) * 8];

  // ================= PASS 1: denominators =================
  gload16(kgsrc, kdst0);
  __syncthreads();   // stage(chunk0) done + ekbits/mkill visible

  float srun[4] = {0.f, 0.f, 0.f, 0.f};
  for (int c = 0; c < 32; c++) {
    int cur = c & 1;
    if (c < 31) gload16(kgsrc + (size_t)(c + 1) * 32 * 512, cur ? kdst0 : kdst1);
    #pragma unroll
    for (int c2 = 0; c2 < 2; c2++) {
      int kt = c * 2 + c2;
      int row = c2 * 16 + lr, r7 = row & 7;
      bf16x8 b0 = *reinterpret_cast<const bf16x8*>(&klds[cur][row * 64 + ((lg ^ r7) << 3)]);
      bf16x8 b1 = *reinterpret_cast<const bf16x8*>(&klds[cur][row * 64 + (((4 + lg) ^ r7) << 3)]);
      f32x4 cc = {0.f, 0.f, 0.f, 0.f};
      cc = __builtin_amdgcn_mfma_f32_16x16x32_bf16(a0, b0, cc, 0, 0, 0);
      cc = __builtin_amdgcn_mfma_f32_16x16x32_bf16(a1, b1, cc, 0, 0, 0);
      int wcol = kt >> 1, bitpos = ((kt & 1) << 4) + lr;
      bool ekb = (ekbits[wcol] >> bitpos) & 1;
      #pragma unroll
      for (int j = 0; j < 4; j++) {
        bool mk = (mkill[qlc[j] * 33 + wcol] >> bitpos) & 1;
        float val = ekb ? (mk ? NEGV : cc[j]) : 0.f;
        srun[j] += __expf(val);
      }
    }
    __syncthreads();
  }
  float rS[4];
  #pragma unroll
  for (int j = 0; j < 4; j++) {
    float s = srun[j];
    s += __shfl_xor(s, 1); s += __shfl_xor(s, 2);
    s += __shfl_xor(s, 4); s += __shfl_xor(s, 8);
    rS[j] = 1.f / s;
  }

  // ================= PASS 2: attn write + PV =================
  f32x4 oacc[4];
  #pragma unroll
  for (int n = 0; n < 4; n++) oacc[n] = {0.f, 0.f, 0.f, 0.f};
  float* ag = attn_g + ((size_t)(b * 8 + h)) * 1024 * 1024;

  gload16(kgsrc, kdst0);
  gload16(vgsrc, vdst0);
  __syncthreads();

  for (int c = 0; c < 32; c++) {
    int cur = c & 1;
    if (c < 31) {
      gload16(kgsrc + (size_t)(c + 1) * 32 * 512, cur ? kdst0 : kdst1);
      gload16(vgsrc + (size_t)(c + 1) * 32, cur ? vdst0 : vdst1);
    }
    #pragma unroll
    for (int c2 = 0; c2 < 2; c2++) {
      int kt = c * 2 + c2;
      int row = c2 * 16 + lr, r7 = row & 7;
      bf16x8 b0 = *reinterpret_cast<const bf16x8*>(&klds[cur][row * 64 + ((lg ^ r7) << 3)]);
      bf16x8 b1 = *reinterpret_cast<const bf16x8*>(&klds[cur][row * 64 + (((4 + lg) ^ r7) << 3)]);
      f32x4 cc = {0.f, 0.f, 0.f, 0.f};
      cc = __builtin_amdgcn_mfma_f32_16x16x32_bf16(a0, b0, cc, 0, 0, 0);
      cc = __builtin_amdgcn_mfma_f32_16x16x32_bf16(a1, b1, cc, 0, 0, 0);
      int wcol = kt >> 1, bitpos = ((kt & 1) << 4) + lr;
      bool ekb = (ekbits[wcol] >> bitpos) & 1;
      int kidx = kt * 16 + lr;
      #pragma unroll
      for (int j = 0; j < 4; j++) {
        bool mk = (mkill[qlc[j] * 33 + wcol] >> bitpos) & 1;
        float val = ekb ? (mk ? NEGV : cc[j]) : 0.f;
        float p = __expf(val) * rS[j];
        __builtin_nontemporal_store(p, &ag[(size_t)qrc[j] * 1024 + kidx]);
        pbuf[w][lg * 4 + j][(kt & 1) * 16 + lr] = f2b(p);
      }
      if (kt & 1) {
        bf16x8 pa = *reinterpret_cast<const bf16x8*>(&pbuf[w][lr][lg * 8]);
        #pragma unroll
        for (int n = 0; n < 4; n++) {
          int vr = n * 16 + lr;
          int cb = (lg ^ ((vr >> 1) & 3)) << 3;
          bf16x8 vb = *reinterpret_cast<const bf16x8*>(&vlds[cur][vr * 32 + cb]);
          oacc[n] = __builtin_amdgcn_mfma_f32_16x16x32_bf16(pa, vb, oacc[n], 0, 0, 0);
        }
      }
    }
    __syncthreads();
  }
  #pragma unroll
  for (int n = 0; n < 4; n++) {
    #pragma unroll
    for (int j = 0; j < 4; j++) {
      __builtin_nontemporal_store(f2b(oacc[n][j]),
          &pv_out[(size_t)(b * 1024 + qrc[j]) * 512 + h * 64 + n * 16 + lr]);
    }
  }
}

extern "C" void kernel_launch(void* const* d_in, const int* in_sizes, int n_in,
                              void* d_out, int out_size, void* d_ws, size_t ws_size,
                              hipStream_t stream) {
  (void)in_sizes; (void)n_in; (void)out_size; (void)ws_size;
  const float* q     = (const float*)d_in[0];
  const float* k     = (const float*)d_in[1];
  const float* v     = (const float*)d_in[2];
  const int* etype   = (const int*)d_in[3];
  const void* mask_raw = d_in[4];
  const float* w_qs  = (const float*)d_in[5];
  const float* w_ex  = (const float*)d_in[6];
  const float* w_ks  = (const float*)d_in[7];
  const float* w_vs  = (const float*)d_in[8];
  const float* w_fc  = (const float*)d_in[9];
  const float* b_fc  = (const float*)d_in[10];
  const float* gamma = (const float*)d_in[11];
  const float* beta  = (const float*)d_in[12];

  char* ws = (char*)d_ws;
  const size_t MB = 1024 * 1024;
  unsigned short* qn   = (unsigned short*)(ws);            // 8 MB bf16
  unsigned short* qen  = (unsigned short*)(ws + 8 * MB);
  unsigned short* qex  = (unsigned short*)(ws + 16 * MB);
  unsigned short* khb  = (unsigned short*)(ws + 24 * MB);
  unsigned short* vhT  = (unsigned short*)(ws + 32 * MB);
  unsigned short* ao   = (unsigned short*)(ws + 40 * MB);
  unsigned int* mbits  = (unsigned int*)(ws + 48 * MB);    // 1 MB
  int* mflag           = (int*)(ws + 49 * MB);

  float* outp = (float*)d_out;
  float* attn_g = outp + (size_t)8 * 1024 * 512;

  ln_kernel<<<8192, 256, 0, stream>>>(q, gamma, beta, qn);

  const int MASK_N = 8 * 1024 * 1024;
  hipMemsetAsync(mflag, 0, 4, stream);
  mask_detect<<<2048, 256, 0, stream>>>((const unsigned int*)mask_raw, MASK_N / 4, mflag);
  const int NWORDS = MASK_N / 32;
  mask_canon_bits<<<(NWORDS + 255) / 256, 256, 0, stream>>>(mask_raw, mbits, NWORDS, mflag);

  dim3 gg(128, 8);
  gemm_bt<0, false, true><<<gg, 256, 0, stream>>>(qn, w_qs, qen, 0.125f, nullptr, nullptr);
  gemm_bt<0, false, true><<<gg, 256, 0, stream>>>(qn, w_ex, qex, 0.125f, nullptr, nullptr);
  gemm_bt<0, true,  true><<<gg, 256, 0, stream>>>(k,  w_ks, khb, 1.0f, nullptr, nullptr);
  gemm_bt<1, true,  true><<<gg, 256, 0, stream>>>(v,  w_vs, vhT, 1.0f, nullptr, nullptr);

  attn_kernel<<<dim3(16, 8, 8), 256, 0, stream>>>(qen, qex, khb, vhT, etype, mbits,
                                                  attn_g, ao);

  gemm_bt<2, false, true><<<gg, 256, 0, stream>>>(ao, w_fc, outp, 1.0f, b_fc, q);
}